// Round 5
// baseline (558.552 us; speedup 1.0000x reference)
//
#include <hip/hip_runtime.h>
#include <hip/hip_bf16.h>

#define B_   4
#define NX_  1024
#define NC_  2048
#define C_   1024
#define H_   16
#define DH_  64

typedef __attribute__((ext_vector_type(8))) __bf16 bf16x8;
typedef __attribute__((ext_vector_type(4))) float  f32x4;

// RNE float->bf16 (inputs finite)
static __device__ __forceinline__ unsigned short f2bf(float f) {
    unsigned int u = __float_as_uint(f);
    u += 0x7fffu + ((u >> 16) & 1u);
    return (unsigned short)(u >> 16);
}

// pack 2 floats -> 2 bf16 (round-half-up)
static __device__ __forceinline__ unsigned int pk2(float lo, float hi) {
    unsigned int a = __float_as_uint(lo) + 0x8000u;
    unsigned int b = __float_as_uint(hi) + 0x8000u;
    return __builtin_amdgcn_perm(b, a, 0x07060302);   // {b.hi16, a.hi16}
}

static __device__ __forceinline__ bf16x8 ldfrag(const unsigned short* p) {
    union { uint4 u; bf16x8 b; } cv;
    cv.u = *reinterpret_cast<const uint4*>(p);
    return cv.b;
}

// ---------------- fused fp32 -> bf16 converts (x, w_qkv, w_proj, cache_k) ----------------
__global__ __launch_bounds__(256) void cvt_all_kernel(
    const float* __restrict__ x,  const float* __restrict__ wq,
    const float* __restrict__ wp, const float* __restrict__ ck,
    unsigned short* __restrict__ xbf,  unsigned short* __restrict__ wqbf,
    unsigned short* __restrict__ wpbf, unsigned short* __restrict__ kfb) {
    int blk = blockIdx.x;
    const float* src; unsigned short* dst; int i;
    if (blk < 4096)      { src = x;  dst = xbf;  i = blk; }
    else if (blk < 7168) { src = wq; dst = wqbf; i = blk - 4096; }
    else if (blk < 8192) { src = wp; dst = wpbf; i = blk - 7168; }
    else                 { src = ck; dst = kfb;  i = blk - 8192; }
    int idx = i * 256 + threadIdx.x;
    float4 f = reinterpret_cast<const float4*>(src)[idx];
    ushort4 o;
    o.x = f2bf(f.x); o.y = f2bf(f.y); o.z = f2bf(f.z); o.w = f2bf(f.w);
    reinterpret_cast<ushort4*>(dst)[idx] = o;
}

// ------- cache_v (B,H,NC,DH) fp32 -> vt (B,H,DH,NC) bf16 (transpose) -------
__global__ __launch_bounds__(256) void vt_cvt_kernel(const float* __restrict__ cv_,
                                                     unsigned short* __restrict__ vt) {
    int t   = threadIdx.x;
    int blk = blockIdx.x;
    int bh  = blk >> 6;
    int kg  = blk & 63;
    int d   = t & 63;
    int kci = t >> 6;
    int kc  = kg * 4 + kci;
    const float* src = cv_ + ((size_t)bh * NC_ + (size_t)kc * 8) * DH_ + d;
    union { uint4 u; unsigned short s[8]; } o;
#pragma unroll
    for (int j = 0; j < 8; j++) o.s[j] = f2bf(src[(size_t)j * DH_]);
    *reinterpret_cast<uint4*>(vt + ((size_t)bh * DH_ + d) * NC_ + (size_t)kc * 8) = o.u;
}

// ---------------- m97-style 128x128 GEMM core (C = A.B^T, K=1024) ----------------
static __device__ __forceinline__ void stage32(const unsigned short* g, unsigned short* lds,
                                               int w, int l) {
#pragma unroll
    for (int i = 0; i < 2; i++) {
        const unsigned short* gp = g + (size_t)(w * 32 + i * 16 + (l >> 2)) * C_ + (l & 3) * 8;
        unsigned short* lp = lds + (w * 32 + i * 16) * 32;   // wave-uniform
        __builtin_amdgcn_global_load_lds((const __attribute__((address_space(1))) void*)gp,
                                         (__attribute__((address_space(3))) void*)lp,
                                         16, 0, 0);
    }
}

static __device__ __forceinline__ void gemm_core(const unsigned short* Ag, const unsigned short* Bg,
                                                 unsigned short* As, unsigned short* Bs,
                                                 int w, int l, int wr, int wc, int quad, int col,
                                                 f32x4 acc[4][4]) {
    for (int kk = 0; kk < C_; kk += 32) {
        __syncthreads();
        stage32(Ag + kk, As, w, l);
        stage32(Bg + kk, Bs, w, l);
        __syncthreads();
        bf16x8 af[4], bfr[4];
#pragma unroll
        for (int t = 0; t < 4; t++) af[t]  = ldfrag(&As[(wr * 64 + t * 16 + col) * 32 + quad * 8]);
#pragma unroll
        for (int t = 0; t < 4; t++) bfr[t] = ldfrag(&Bs[(wc * 64 + t * 16 + col) * 32 + quad * 8]);
#pragma unroll
        for (int mt = 0; mt < 4; mt++)
#pragma unroll
            for (int nt = 0; nt < 4; nt++)
                acc[mt][nt] = __builtin_amdgcn_mfma_f32_16x16x32_bf16(af[mt], bfr[nt], acc[mt][nt], 0, 0, 0);
    }
}

// ---------------- QKV GEMM (4096x1024)x(3072x1024)^T + scatter epilogue ----------------
__global__ __launch_bounds__(256) void qkv_gemm_kernel(
    const unsigned short* __restrict__ xbf,
    const unsigned short* __restrict__ wbf,
    const float* __restrict__ bias,
    const int* __restrict__ uidx,
    unsigned short* __restrict__ qb,   // (B,H,NX,DH) scaled by 0.125*log2(e)
    unsigned short* __restrict__ kf,   // (B,H,NC,DH)
    unsigned short* __restrict__ vt)   // (B,H,DH,NC)
{
    __shared__ unsigned short As[128 * 32], Bs[128 * 32];
    int bn = blockIdx.x, bm = blockIdx.y;
    int w = threadIdx.x >> 6, l = threadIdx.x & 63;
    int quad = l >> 4, col = l & 15;
    int wr = w >> 1, wc = w & 1;
    f32x4 acc[4][4];
#pragma unroll
    for (int a = 0; a < 4; a++)
#pragma unroll
        for (int b = 0; b < 4; b++) acc[a][b] = (f32x4){0.f, 0.f, 0.f, 0.f};

    gemm_core(xbf + (size_t)(bm * 128) * C_, wbf + (size_t)(bn * 128) * C_,
              As, Bs, w, l, wr, wc, quad, col, acc);

    int part = bn >> 3;             // 0=q 1=k 2=v
    float bv[4]; int nl[4];
#pragma unroll
    for (int nt = 0; nt < 4; nt++) {
        int n = bn * 128 + wc * 64 + nt * 16 + col;
        bv[nt] = bias[n];
        nl[nt] = n & 1023;
    }
    const float QS = 0.18033688011112042f;   // 0.125 * log2(e)
#pragma unroll
    for (int mt = 0; mt < 4; mt++)
#pragma unroll
        for (int r = 0; r < 4; r++) {
            int m = bm * 128 + wr * 64 + mt * 16 + quad * 4 + r;
            int b = m >> 10, i = m & 1023;
            int j = (part == 0) ? 0 : uidx[(b << 10) + i];
#pragma unroll
            for (int nt = 0; nt < 4; nt++) {
                int h = nl[nt] >> 6, d = nl[nt] & 63;
                float v = acc[mt][nt][r] + bv[nt];
                if (part == 0)
                    qb[((size_t)(b * H_ + h) * NX_ + i) * DH_ + d] = f2bf(v * QS);
                else if (part == 1)
                    kf[((size_t)(b * H_ + h) * NC_ + j) * DH_ + d] = f2bf(v);
                else
                    vt[((size_t)(b * H_ + h) * DH_ + d) * NC_ + j] = f2bf(v);
            }
        }
}

// ---------------- flash attention: no-max softmax, skewed pipeline, key-split waves ----------------
// grid (32, 64): block = 32 queries. Wave (qw=wave&1, kh=wave>>1) handles
// queries qt*32+qw*16..+15 over keys kh*1024..+1023 (32 iters x 32 keys).
// m==0 softmax => key-split partials merge by PLAIN ADDITION of (O,l) at the
// end (one LDS round-trip + one barrier). 2048 blocks = 8 blocks/CU = 100%
// occupancy cap; latency hidden by TLP instead of prefetch depth.
#define PST 40   // P row stride (32 keys + 8 pad) ushorts
__global__ __launch_bounds__(256, 8) void attn_kernel(
    const unsigned short* __restrict__ qb,
    const unsigned short* __restrict__ kf,
    const unsigned short* __restrict__ vt,
    unsigned short* __restrict__ ao)          // (B,NX,C) bf16
{
    __shared__ unsigned short Psh[4][2][16 * PST];   // 10240 B
    __shared__ float Om[2][64][17];                  // 8704 B
    __shared__ float Lm[2][64];                      // 512 B
    int qt = blockIdx.x;    // 0..31  (32-query group)
    int bh = blockIdx.y;    // 0..63
    int wave = threadIdx.x >> 6, lane = threadIdx.x & 63;
    int quad = lane >> 4, col = lane & 15;
    int qw = wave & 1;      // query half within block
    int kh = wave >> 1;     // key half

    const unsigned short* qrow = qb + ((size_t)bh * NX_ + qt * 32 + qw * 16 + col) * DH_;
    bf16x8 qf0 = ldfrag(qrow + quad * 8);
    bf16x8 qf1 = ldfrag(qrow + 32 + quad * 8);

    const unsigned short* kbase = kf + ((size_t)bh * NC_ + kh * 1024) * DH_;
    const unsigned short* vbase = vt + (size_t)bh * DH_ * NC_ + kh * 1024;
    unsigned short* Pb0 = &Psh[wave][0][0];
    unsigned short* Pb1 = &Psh[wave][1][0];

    f32x4 o[4];
#pragma unroll
    for (int t = 0; t < 4; t++) o[t] = (f32x4){0.f, 0.f, 0.f, 0.f};
    float l_i = 0.f;

    bf16x8 kA[2][2], kB[2][2], vf[4];

#define LOADK(slot, kb_)                                                            \
    {                                                                               \
        _Pragma("unroll")                                                           \
        for (int t = 0; t < 2; t++) {                                               \
            const unsigned short* kr = kbase + (size_t)((kb_) * 32 + t * 16 + col) * DH_ + quad * 8; \
            kA[slot][t] = ldfrag(kr);                                               \
            kB[slot][t] = ldfrag(kr + 32);                                          \
        }                                                                           \
    }
#define LOADV(kb_)                                                                  \
    {                                                                               \
        _Pragma("unroll")                                                           \
        for (int t = 0; t < 4; t++)                                                 \
            vf[t] = ldfrag(vbase + (size_t)(t * 16 + col) * NC_ + (kb_) * 32 + quad * 8); \
    }
#define SCORE(slot, s0, s1)                                                         \
    {                                                                               \
        s0 = (f32x4){0.f, 0.f, 0.f, 0.f};                                           \
        s1 = (f32x4){0.f, 0.f, 0.f, 0.f};                                           \
        s0 = __builtin_amdgcn_mfma_f32_16x16x32_bf16(kA[slot][0], qf0, s0, 0, 0, 0);\
        s0 = __builtin_amdgcn_mfma_f32_16x16x32_bf16(kB[slot][0], qf1, s0, 0, 0, 0);\
        s1 = __builtin_amdgcn_mfma_f32_16x16x32_bf16(kA[slot][1], qf0, s1, 0, 0, 0);\
        s1 = __builtin_amdgcn_mfma_f32_16x16x32_bf16(kB[slot][1], qf1, s1, 0, 0, 0);\
    }
#define SOFTMAX(s0, s1, Pb)                                                         \
    {                                                                               \
        float p0 = exp2f(s0[0]), p1 = exp2f(s0[1]), p2 = exp2f(s0[2]), p3 = exp2f(s0[3]); \
        float p4 = exp2f(s1[0]), p5 = exp2f(s1[1]), p6 = exp2f(s1[2]), p7 = exp2f(s1[3]); \
        l_i += ((p0 + p1) + (p2 + p3)) + ((p4 + p5) + (p6 + p7));                   \
        uint2 w0; w0.x = pk2(p0, p1); w0.y = pk2(p2, p3);                           \
        uint2 w1; w1.x = pk2(p4, p5); w1.y = pk2(p6, p7);                           \
        *reinterpret_cast<uint2*>(&(Pb)[col * PST +      quad * 4]) = w0;           \
        *reinterpret_cast<uint2*>(&(Pb)[col * PST + 16 + quad * 4]) = w1;           \
    }
#define PV(Pb)                                                                      \
    {                                                                               \
        bf16x8 pf = ldfrag(&(Pb)[col * PST + quad * 8]);                            \
        _Pragma("unroll")                                                           \
        for (int t = 0; t < 4; t++)                                                 \
            o[t] = __builtin_amdgcn_mfma_f32_16x16x32_bf16(vf[t], pf, o[t], 0, 0, 0); \
    }

    // ---- prologue: iter 0 ----
    LOADK(0, 0);
    {
        f32x4 s0, s1;
        SCORE(0, s0, s1);
        LOADK(1, 1);
        LOADV(0);
        SOFTMAX(s0, s1, Pb0);
    }
    // ---- main loop: iters 1..30 (x2 unroll for static slots) ----
#pragma unroll 1
    for (int ii = 0; ii < 15; ii++) {
        int i = 2 * ii + 1;                 // odd iter: cur slot 1, prev P = Pb0
        {
            f32x4 s0, s1;
            SCORE(1, s0, s1);
            LOADK(0, (i + 1) & 31);
            PV(Pb0);                        // PV_{i-1}, vf from prev iter
            LOADV(i);
            SOFTMAX(s0, s1, Pb1);
        }
        {                                   // even iter i+1: cur slot 0, prev P = Pb1
            f32x4 s0, s1;
            SCORE(0, s0, s1);
            LOADK(1, (i + 2) & 31);
            PV(Pb1);
            LOADV(i + 1);
            SOFTMAX(s0, s1, Pb0);
        }
    }
    {                                       // iter 31 (odd)
        f32x4 s0, s1;
        SCORE(1, s0, s1);
        PV(Pb0);
        LOADV(31);
        SOFTMAX(s0, s1, Pb1);
    }
    PV(Pb1);                                // epilogue PV_31

    // ---- l across quads (same query = same col) ----
    l_i += __shfl_xor(l_i, 16, 64);
    l_i += __shfl_xor(l_i, 32, 64);

    // ---- merge key halves: plain (O,l) addition (m==0) ----
    if (kh == 1) {
#pragma unroll
        for (int t = 0; t < 4; t++)
#pragma unroll
            for (int r = 0; r < 4; r++)
                Om[qw][lane][t * 4 + r] = o[t][r];
        Lm[qw][lane] = l_i;
    }
    __syncthreads();
    if (kh == 0) {
        l_i += Lm[qw][lane];
        float inv = 1.f / l_i;
        int b = bh >> 4, h = bh & 15;
        int q = qt * 32 + qw * 16 + col;
        unsigned short* orow = ao + ((size_t)b * NX_ + q) * C_ + h * 64;
#pragma unroll
        for (int t = 0; t < 4; t++) {
            float v0 = (o[t][0] + Om[qw][lane][t * 4 + 0]) * inv;
            float v1 = (o[t][1] + Om[qw][lane][t * 4 + 1]) * inv;
            float v2 = (o[t][2] + Om[qw][lane][t * 4 + 2]) * inv;
            float v3 = (o[t][3] + Om[qw][lane][t * 4 + 3]) * inv;
            uint2 ov;
            ov.x = pk2(v0, v1);
            ov.y = pk2(v2, v3);
            *reinterpret_cast<uint2*>(&orow[t * 16 + quad * 4]) = ov;
        }
    }
#undef LOADK
#undef LOADV
#undef SCORE
#undef SOFTMAX
#undef PV
}

// ---------------- projection GEMM (4096x1024)x(1024x1024)^T + bias ----------------
__global__ __launch_bounds__(256) void proj_gemm_kernel(
    const unsigned short* __restrict__ abf,
    const unsigned short* __restrict__ wbf,
    const float* __restrict__ bias,
    float* __restrict__ out)
{
    __shared__ unsigned short As[128 * 32], Bs[128 * 32];
    int bn = blockIdx.x, bm = blockIdx.y;
    int w = threadIdx.x >> 6, l = threadIdx.x & 63;
    int quad = l >> 4, col = l & 15;
    int wr = w >> 1, wc = w & 1;
    f32x4 acc[4][4];
#pragma unroll
    for (int a = 0; a < 4; a++)
#pragma unroll
        for (int b = 0; b < 4; b++) acc[a][b] = (f32x4){0.f, 0.f, 0.f, 0.f};

    gemm_core(abf + (size_t)(bm * 128) * C_, wbf + (size_t)(bn * 128) * C_,
              As, Bs, w, l, wr, wc, quad, col, acc);

    float bv[4];
#pragma unroll
    for (int nt = 0; nt < 4; nt++) bv[nt] = bias[bn * 128 + wc * 64 + nt * 16 + col];
#pragma unroll
    for (int mt = 0; mt < 4; mt++)
#pragma unroll
        for (int r = 0; r < 4; r++) {
            int m = bm * 128 + wr * 64 + mt * 16 + quad * 4 + r;
#pragma unroll
            for (int nt = 0; nt < 4; nt++) {
                int n = bn * 128 + wc * 64 + nt * 16 + col;
                out[(size_t)m * C_ + n] = acc[mt][nt][r] + bv[nt];
            }
        }
}

extern "C" void kernel_launch(void* const* d_in, const int* in_sizes, int n_in,
                              void* d_out, int out_size, void* d_ws, size_t ws_size,
                              hipStream_t stream) {
    const float* x      = (const float*)d_in[0];
    const int*   uidx   = (const int*)  d_in[1];
    const float* cachek = (const float*)d_in[2];
    const float* cachev = (const float*)d_in[3];
    const float* wqkv   = (const float*)d_in[4];
    const float* bqkv   = (const float*)d_in[5];
    const float* wproj  = (const float*)d_in[6];
    const float* bproj  = (const float*)d_in[7];
    float* out = (float*)d_out;

    char* ws = (char*)d_ws;
    unsigned short* xbf  = (unsigned short*)(ws);                       // 8 MB
    unsigned short* wqbf = (unsigned short*)(ws + (8ull  << 20));       // 6 MB
    unsigned short* wpbf = (unsigned short*)(ws + (14ull << 20));       // 2 MB
    unsigned short* qb   = (unsigned short*)(ws + (16ull << 20));       // 8 MB
    unsigned short* kfb  = (unsigned short*)(ws + (24ull << 20));       // 16 MB
    unsigned short* vtb  = (unsigned short*)(ws + (40ull << 20));       // 16 MB
    unsigned short* aob  = (unsigned short*)(ws + (56ull << 20));       // 8 MB

    cvt_all_kernel<<<16384, 256, 0, stream>>>(x, wqkv, wproj, cachek, xbf, wqbf, wpbf, kfb);
    vt_cvt_kernel <<<4096, 256, 0, stream>>>(cachev, vtb);

    qkv_gemm_kernel <<<dim3(24, 32), 256, 0, stream>>>(xbf, wqbf, bqkv, uidx, qb, kfb, vtb);
    attn_kernel     <<<dim3(32, 64), 256, 0, stream>>>(qb, kfb, vtb, aob);
    proj_gemm_kernel<<<dim3(8, 32),  256, 0, stream>>>(aob, wpbf, bproj, out);
}

// Round 6
// 444.979 us; speedup vs baseline: 1.2552x; 1.2552x over previous
//
#include <hip/hip_runtime.h>
#include <hip/hip_bf16.h>

#define B_   4
#define NX_  1024
#define NC_  2048
#define C_   1024
#define H_   16
#define DH_  64

typedef __attribute__((ext_vector_type(8))) __bf16 bf16x8;
typedef __attribute__((ext_vector_type(4))) float  f32x4;

// RNE float->bf16 (inputs finite)
static __device__ __forceinline__ unsigned short f2bf(float f) {
    unsigned int u = __float_as_uint(f);
    u += 0x7fffu + ((u >> 16) & 1u);
    return (unsigned short)(u >> 16);
}

// pack 2 floats -> 2 bf16 (round-half-up)
static __device__ __forceinline__ unsigned int pk2(float lo, float hi) {
    unsigned int a = __float_as_uint(lo) + 0x8000u;
    unsigned int b = __float_as_uint(hi) + 0x8000u;
    return __builtin_amdgcn_perm(b, a, 0x07060302);   // {b.hi16, a.hi16}
}

static __device__ __forceinline__ bf16x8 ldfrag(const unsigned short* p) {
    union { uint4 u; bf16x8 b; } cv;
    cv.u = *reinterpret_cast<const uint4*>(p);
    return cv.b;
}

// ---------------- fused fp32 -> bf16 converts (x, w_qkv, w_proj, cache_k) ----------------
__global__ __launch_bounds__(256) void cvt_all_kernel(
    const float* __restrict__ x,  const float* __restrict__ wq,
    const float* __restrict__ wp, const float* __restrict__ ck,
    unsigned short* __restrict__ xbf,  unsigned short* __restrict__ wqbf,
    unsigned short* __restrict__ wpbf, unsigned short* __restrict__ kfb) {
    int blk = blockIdx.x;
    const float* src; unsigned short* dst; int i;
    if (blk < 4096)      { src = x;  dst = xbf;  i = blk; }
    else if (blk < 7168) { src = wq; dst = wqbf; i = blk - 4096; }
    else if (blk < 8192) { src = wp; dst = wpbf; i = blk - 7168; }
    else                 { src = ck; dst = kfb;  i = blk - 8192; }
    int idx = i * 256 + threadIdx.x;
    float4 f = reinterpret_cast<const float4*>(src)[idx];
    ushort4 o;
    o.x = f2bf(f.x); o.y = f2bf(f.y); o.z = f2bf(f.z); o.w = f2bf(f.w);
    reinterpret_cast<ushort4*>(dst)[idx] = o;
}

// ------- cache_v (B,H,NC,DH) fp32 -> vt (B,H,DH,NC) bf16 (transpose) -------
__global__ __launch_bounds__(256) void vt_cvt_kernel(const float* __restrict__ cv_,
                                                     unsigned short* __restrict__ vt) {
    int t   = threadIdx.x;
    int blk = blockIdx.x;
    int bh  = blk >> 6;
    int kg  = blk & 63;
    int d   = t & 63;
    int kci = t >> 6;
    int kc  = kg * 4 + kci;
    const float* src = cv_ + ((size_t)bh * NC_ + (size_t)kc * 8) * DH_ + d;
    union { uint4 u; unsigned short s[8]; } o;
#pragma unroll
    for (int j = 0; j < 8; j++) o.s[j] = f2bf(src[(size_t)j * DH_]);
    *reinterpret_cast<uint4*>(vt + ((size_t)bh * DH_ + d) * NC_ + (size_t)kc * 8) = o.u;
}

// ---------------- m97-style 128x128 GEMM core (C = A.B^T, K=1024) ----------------
static __device__ __forceinline__ void stage32(const unsigned short* g, unsigned short* lds,
                                               int w, int l) {
#pragma unroll
    for (int i = 0; i < 2; i++) {
        const unsigned short* gp = g + (size_t)(w * 32 + i * 16 + (l >> 2)) * C_ + (l & 3) * 8;
        unsigned short* lp = lds + (w * 32 + i * 16) * 32;   // wave-uniform
        __builtin_amdgcn_global_load_lds((const __attribute__((address_space(1))) void*)gp,
                                         (__attribute__((address_space(3))) void*)lp,
                                         16, 0, 0);
    }
}

static __device__ __forceinline__ void gemm_core(const unsigned short* Ag, const unsigned short* Bg,
                                                 unsigned short* As, unsigned short* Bs,
                                                 int w, int l, int wr, int wc, int quad, int col,
                                                 f32x4 acc[4][4]) {
    for (int kk = 0; kk < C_; kk += 32) {
        __syncthreads();
        stage32(Ag + kk, As, w, l);
        stage32(Bg + kk, Bs, w, l);
        __syncthreads();
        bf16x8 af[4], bfr[4];
#pragma unroll
        for (int t = 0; t < 4; t++) af[t]  = ldfrag(&As[(wr * 64 + t * 16 + col) * 32 + quad * 8]);
#pragma unroll
        for (int t = 0; t < 4; t++) bfr[t] = ldfrag(&Bs[(wc * 64 + t * 16 + col) * 32 + quad * 8]);
#pragma unroll
        for (int mt = 0; mt < 4; mt++)
#pragma unroll
            for (int nt = 0; nt < 4; nt++)
                acc[mt][nt] = __builtin_amdgcn_mfma_f32_16x16x32_bf16(af[mt], bfr[nt], acc[mt][nt], 0, 0, 0);
    }
}

// ---------------- QKV GEMM (4096x1024)x(3072x1024)^T + scatter epilogue ----------------
__global__ __launch_bounds__(256) void qkv_gemm_kernel(
    const unsigned short* __restrict__ xbf,
    const unsigned short* __restrict__ wbf,
    const float* __restrict__ bias,
    const int* __restrict__ uidx,
    unsigned short* __restrict__ qb,   // (B,H,NX,DH) scaled by 0.125*log2(e)
    unsigned short* __restrict__ kf,   // (B,H,NC,DH)
    unsigned short* __restrict__ vt)   // (B,H,DH,NC)
{
    __shared__ unsigned short As[128 * 32], Bs[128 * 32];
    int bn = blockIdx.x, bm = blockIdx.y;
    int w = threadIdx.x >> 6, l = threadIdx.x & 63;
    int quad = l >> 4, col = l & 15;
    int wr = w >> 1, wc = w & 1;
    f32x4 acc[4][4];
#pragma unroll
    for (int a = 0; a < 4; a++)
#pragma unroll
        for (int b = 0; b < 4; b++) acc[a][b] = (f32x4){0.f, 0.f, 0.f, 0.f};

    gemm_core(xbf + (size_t)(bm * 128) * C_, wbf + (size_t)(bn * 128) * C_,
              As, Bs, w, l, wr, wc, quad, col, acc);

    int part = bn >> 3;             // 0=q 1=k 2=v
    float bv[4]; int nl[4];
#pragma unroll
    for (int nt = 0; nt < 4; nt++) {
        int n = bn * 128 + wc * 64 + nt * 16 + col;
        bv[nt] = bias[n];
        nl[nt] = n & 1023;
    }
    const float QS = 0.18033688011112042f;   // 0.125 * log2(e)
#pragma unroll
    for (int mt = 0; mt < 4; mt++)
#pragma unroll
        for (int r = 0; r < 4; r++) {
            int m = bm * 128 + wr * 64 + mt * 16 + quad * 4 + r;
            int b = m >> 10, i = m & 1023;
            int j = (part == 0) ? 0 : uidx[(b << 10) + i];
#pragma unroll
            for (int nt = 0; nt < 4; nt++) {
                int h = nl[nt] >> 6, d = nl[nt] & 63;
                float v = acc[mt][nt][r] + bv[nt];
                if (part == 0)
                    qb[((size_t)(b * H_ + h) * NX_ + i) * DH_ + d] = f2bf(v * QS);
                else if (part == 1)
                    kf[((size_t)(b * H_ + h) * NC_ + j) * DH_ + d] = f2bf(v);
                else
                    vt[((size_t)(b * H_ + h) * DH_ + d) * NC_ + j] = f2bf(v);
            }
        }
}

// ---------------- flash attention: no-max softmax, depth-2 pipeline, XCD-swizzled ----------------
// 1024 flat blocks; decode so id%8 == bh%8: all 16 q-tiles of one bh land on
// the same XCD (round-robin dispatch), giving per-XCD L2 working set of
// 8 bh x 512 KB = 4 MB (= L2 size) instead of 32 MB interleaved.
// Per wave: 16 queries x all 2048 keys, 64 iters x 32 keys.
// Depth-2 prefetch: K_{i+2}/V_{i+1} issued in iter i into the just-freed
// slot -> ~2 iters (~560 cy at 4 waves/SIMD) of latency cover vs ~430 cy
// measured avg load latency. VGPR ~70 < 128 cap at (256,4): no spills.
#define PST 40   // P row stride (32 keys + 8 pad) ushorts
__global__ __launch_bounds__(256, 4) void attn_kernel(
    const unsigned short* __restrict__ qb,
    const unsigned short* __restrict__ kf,
    const unsigned short* __restrict__ vt,
    unsigned short* __restrict__ ao)          // (B,NX,C) bf16
{
    __shared__ unsigned short Psh[4][2][16 * PST];   // 10240 B
    int id = blockIdx.x;
    int qt = (id >> 3) & 15;               // 0..15
    int bh = ((id >> 7) << 3) | (id & 7);  // 0..63, id%8 == bh%8
    int wave = threadIdx.x >> 6, lane = threadIdx.x & 63;
    int quad = lane >> 4, col = lane & 15;

    const unsigned short* qrow = qb + ((size_t)bh * NX_ + qt * 64 + wave * 16 + col) * DH_;
    bf16x8 qf0 = ldfrag(qrow + quad * 8);
    bf16x8 qf1 = ldfrag(qrow + 32 + quad * 8);

    const unsigned short* kbase = kf + (size_t)bh * NC_ * DH_;
    const unsigned short* vbase = vt + (size_t)bh * DH_ * NC_;
    unsigned short* Pb0 = &Psh[wave][0][0];
    unsigned short* Pb1 = &Psh[wave][1][0];

    f32x4 o[4];
#pragma unroll
    for (int t = 0; t < 4; t++) o[t] = (f32x4){0.f, 0.f, 0.f, 0.f};
    float l_i = 0.f;

    bf16x8 kA[2][2], kB[2][2], vf[2][4];

#define LOADK(slot, kb_)                                                            \
    {                                                                               \
        _Pragma("unroll")                                                           \
        for (int t = 0; t < 2; t++) {                                               \
            const unsigned short* kr = kbase + (size_t)(((kb_) & 63) * 32 + t * 16 + col) * DH_ + quad * 8; \
            kA[slot][t] = ldfrag(kr);                                               \
            kB[slot][t] = ldfrag(kr + 32);                                          \
        }                                                                           \
    }
#define LOADV(slot, kb_)                                                            \
    {                                                                               \
        _Pragma("unroll")                                                           \
        for (int t = 0; t < 4; t++)                                                 \
            vf[slot][t] = ldfrag(vbase + (size_t)(t * 16 + col) * NC_ + ((kb_) & 63) * 32 + quad * 8); \
    }
#define SCORE(slot, s0, s1)                                                         \
    {                                                                               \
        s0 = (f32x4){0.f, 0.f, 0.f, 0.f};                                           \
        s1 = (f32x4){0.f, 0.f, 0.f, 0.f};                                           \
        s0 = __builtin_amdgcn_mfma_f32_16x16x32_bf16(kA[slot][0], qf0, s0, 0, 0, 0);\
        s0 = __builtin_amdgcn_mfma_f32_16x16x32_bf16(kB[slot][0], qf1, s0, 0, 0, 0);\
        s1 = __builtin_amdgcn_mfma_f32_16x16x32_bf16(kA[slot][1], qf0, s1, 0, 0, 0);\
        s1 = __builtin_amdgcn_mfma_f32_16x16x32_bf16(kB[slot][1], qf1, s1, 0, 0, 0);\
    }
#define SOFTMAX(s0, s1, Pb)                                                         \
    {                                                                               \
        float p0 = exp2f(s0[0]), p1 = exp2f(s0[1]), p2 = exp2f(s0[2]), p3 = exp2f(s0[3]); \
        float p4 = exp2f(s1[0]), p5 = exp2f(s1[1]), p6 = exp2f(s1[2]), p7 = exp2f(s1[3]); \
        l_i += ((p0 + p1) + (p2 + p3)) + ((p4 + p5) + (p6 + p7));                   \
        uint2 w0; w0.x = pk2(p0, p1); w0.y = pk2(p2, p3);                           \
        uint2 w1; w1.x = pk2(p4, p5); w1.y = pk2(p6, p7);                           \
        *reinterpret_cast<uint2*>(&(Pb)[col * PST +      quad * 4]) = w0;           \
        *reinterpret_cast<uint2*>(&(Pb)[col * PST + 16 + quad * 4]) = w1;           \
    }
#define PV(Pb, vslot)                                                               \
    {                                                                               \
        bf16x8 pf = ldfrag(&(Pb)[col * PST + quad * 8]);                            \
        _Pragma("unroll")                                                           \
        for (int t = 0; t < 4; t++)                                                 \
            o[t] = __builtin_amdgcn_mfma_f32_16x16x32_bf16(vf[vslot][t], pf, o[t], 0, 0, 0); \
    }

    // ---- prologue: K_0, K_1, V_0 in flight ----
    LOADK(0, 0);
    LOADK(1, 1);
    LOADV(0, 0);
    // ---- iter 0 ----
    {
        f32x4 s0, s1;
        SCORE(0, s0, s1);
        LOADK(0, 2);          // K_2 into freed slot 0
        LOADV(1, 1);          // V_1
        SOFTMAX(s0, s1, Pb0); // P_0
    }
    // ---- main loop: iters 1..62, x2 unroll (odd, even) ----
#pragma unroll 1
    for (int ii = 0; ii < 31; ii++) {
        int i = 2 * ii + 1;
        {   // odd iter i: K slot 1, consume V_{i-1}(slot 0), P_{i-1}=Pb0
            f32x4 s0, s1;
            SCORE(1, s0, s1);
            LOADK(1, i + 2);
            PV(Pb0, 0);
            LOADV(0, i + 1);
            SOFTMAX(s0, s1, Pb1);
        }
        {   // even iter i+1: K slot 0, consume V_i(slot 1), P_i=Pb1
            f32x4 s0, s1;
            SCORE(0, s0, s1);
            LOADK(0, i + 3);
            PV(Pb1, 1);
            LOADV(1, i + 2);
            SOFTMAX(s0, s1, Pb0);
        }
    }
    // ---- iter 63 (odd) ----
    {
        f32x4 s0, s1;
        SCORE(1, s0, s1);
        PV(Pb0, 0);           // P_62 . V_62
        SOFTMAX(s0, s1, Pb1); // P_63
    }
    PV(Pb1, 1);               // P_63 . V_63

    // ---- l across quads (same query = same col) ----
    l_i += __shfl_xor(l_i, 16, 64);
    l_i += __shfl_xor(l_i, 32, 64);
    float inv = 1.f / l_i;

    int b = bh >> 4, h = bh & 15;
    int q = qt * 64 + wave * 16 + col;
    unsigned short* orow = ao + ((size_t)b * NX_ + q) * C_ + h * 64;
#pragma unroll
    for (int t = 0; t < 4; t++) {
        uint2 ov;
        ov.x = pk2(o[t][0] * inv, o[t][1] * inv);
        ov.y = pk2(o[t][2] * inv, o[t][3] * inv);
        *reinterpret_cast<uint2*>(&orow[t * 16 + quad * 4]) = ov;
    }
#undef LOADK
#undef LOADV
#undef SCORE
#undef SOFTMAX
#undef PV
}

// ---------------- projection GEMM (4096x1024)x(1024x1024)^T + bias ----------------
__global__ __launch_bounds__(256) void proj_gemm_kernel(
    const unsigned short* __restrict__ abf,
    const unsigned short* __restrict__ wbf,
    const float* __restrict__ bias,
    float* __restrict__ out)
{
    __shared__ unsigned short As[128 * 32], Bs[128 * 32];
    int bn = blockIdx.x, bm = blockIdx.y;
    int w = threadIdx.x >> 6, l = threadIdx.x & 63;
    int quad = l >> 4, col = l & 15;
    int wr = w >> 1, wc = w & 1;
    f32x4 acc[4][4];
#pragma unroll
    for (int a = 0; a < 4; a++)
#pragma unroll
        for (int b = 0; b < 4; b++) acc[a][b] = (f32x4){0.f, 0.f, 0.f, 0.f};

    gemm_core(abf + (size_t)(bm * 128) * C_, wbf + (size_t)(bn * 128) * C_,
              As, Bs, w, l, wr, wc, quad, col, acc);

    float bv[4];
#pragma unroll
    for (int nt = 0; nt < 4; nt++) bv[nt] = bias[bn * 128 + wc * 64 + nt * 16 + col];
#pragma unroll
    for (int mt = 0; mt < 4; mt++)
#pragma unroll
        for (int r = 0; r < 4; r++) {
            int m = bm * 128 + wr * 64 + mt * 16 + quad * 4 + r;
#pragma unroll
            for (int nt = 0; nt < 4; nt++) {
                int n = bn * 128 + wc * 64 + nt * 16 + col;
                out[(size_t)m * C_ + n] = acc[mt][nt][r] + bv[nt];
            }
        }
}

extern "C" void kernel_launch(void* const* d_in, const int* in_sizes, int n_in,
                              void* d_out, int out_size, void* d_ws, size_t ws_size,
                              hipStream_t stream) {
    const float* x      = (const float*)d_in[0];
    const int*   uidx   = (const int*)  d_in[1];
    const float* cachek = (const float*)d_in[2];
    const float* cachev = (const float*)d_in[3];
    const float* wqkv   = (const float*)d_in[4];
    const float* bqkv   = (const float*)d_in[5];
    const float* wproj  = (const float*)d_in[6];
    const float* bproj  = (const float*)d_in[7];
    float* out = (float*)d_out;

    char* ws = (char*)d_ws;
    unsigned short* xbf  = (unsigned short*)(ws);                       // 8 MB
    unsigned short* wqbf = (unsigned short*)(ws + (8ull  << 20));       // 6 MB
    unsigned short* wpbf = (unsigned short*)(ws + (14ull << 20));       // 2 MB
    unsigned short* qb   = (unsigned short*)(ws + (16ull << 20));       // 8 MB
    unsigned short* kfb  = (unsigned short*)(ws + (24ull << 20));       // 16 MB
    unsigned short* vtb  = (unsigned short*)(ws + (40ull << 20));       // 16 MB
    unsigned short* aob  = (unsigned short*)(ws + (56ull << 20));       // 8 MB

    cvt_all_kernel<<<16384, 256, 0, stream>>>(x, wqkv, wproj, cachek, xbf, wqbf, wpbf, kfb);
    vt_cvt_kernel <<<4096, 256, 0, stream>>>(cachev, vtb);

    qkv_gemm_kernel <<<dim3(24, 32), 256, 0, stream>>>(xbf, wqbf, bqkv, uidx, qb, kfb, vtb);
    attn_kernel     <<<1024, 256, 0, stream>>>(qb, kfb, vtb, aob);
    proj_gemm_kernel<<<dim3(8, 32),  256, 0, stream>>>(aob, wpbf, bproj, out);
}

// Round 7
// 282.419 us; speedup vs baseline: 1.9777x; 1.5756x over previous
//
#include <hip/hip_runtime.h>
#include <hip/hip_bf16.h>

#define B_   4
#define NX_  1024
#define NC_  2048
#define C_   1024
#define H_   16
#define DH_  64

typedef __attribute__((ext_vector_type(8))) __bf16 bf16x8;
typedef __attribute__((ext_vector_type(4))) float  f32x4;

// RNE float->bf16 (inputs finite)
static __device__ __forceinline__ unsigned short f2bf(float f) {
    unsigned int u = __float_as_uint(f);
    u += 0x7fffu + ((u >> 16) & 1u);
    return (unsigned short)(u >> 16);
}

// pack 2 floats -> 2 bf16 (round-half-up)
static __device__ __forceinline__ unsigned int pk2(float lo, float hi) {
    unsigned int a = __float_as_uint(lo) + 0x8000u;
    unsigned int b = __float_as_uint(hi) + 0x8000u;
    return __builtin_amdgcn_perm(b, a, 0x07060302);   // {b.hi16, a.hi16}
}

static __device__ __forceinline__ bf16x8 ldfrag(const unsigned short* p) {
    union { uint4 u; bf16x8 b; } cv;
    cv.u = *reinterpret_cast<const uint4*>(p);
    return cv.b;
}

static __device__ __forceinline__ void gl_lds(const unsigned short* g, unsigned short* l) {
    __builtin_amdgcn_global_load_lds((const __attribute__((address_space(1))) void*)g,
                                     (__attribute__((address_space(3))) void*)l, 16, 0, 0);
}

// ---------------- fused fp32 -> bf16 converts (x, w_qkv, w_proj, cache_k) ----------------
__global__ __launch_bounds__(256) void cvt_all_kernel(
    const float* __restrict__ x,  const float* __restrict__ wq,
    const float* __restrict__ wp, const float* __restrict__ ck,
    unsigned short* __restrict__ xbf,  unsigned short* __restrict__ wqbf,
    unsigned short* __restrict__ wpbf, unsigned short* __restrict__ kfb) {
    int blk = blockIdx.x;
    const float* src; unsigned short* dst; int i;
    if (blk < 4096)      { src = x;  dst = xbf;  i = blk; }
    else if (blk < 7168) { src = wq; dst = wqbf; i = blk - 4096; }
    else if (blk < 8192) { src = wp; dst = wpbf; i = blk - 7168; }
    else                 { src = ck; dst = kfb;  i = blk - 8192; }
    int idx = i * 256 + threadIdx.x;
    float4 f = reinterpret_cast<const float4*>(src)[idx];
    ushort4 o;
    o.x = f2bf(f.x); o.y = f2bf(f.y); o.z = f2bf(f.z); o.w = f2bf(f.w);
    reinterpret_cast<ushort4*>(dst)[idx] = o;
}

// ------- cache_v (B,H,NC,DH) fp32 -> vt (B,H,DH,NC) bf16 (transpose) -------
__global__ __launch_bounds__(256) void vt_cvt_kernel(const float* __restrict__ cv_,
                                                     unsigned short* __restrict__ vt) {
    int t   = threadIdx.x;
    int blk = blockIdx.x;
    int bh  = blk >> 6;
    int kg  = blk & 63;
    int d   = t & 63;
    int kci = t >> 6;
    int kc  = kg * 4 + kci;
    const float* src = cv_ + ((size_t)bh * NC_ + (size_t)kc * 8) * DH_ + d;
    union { uint4 u; unsigned short s[8]; } o;
#pragma unroll
    for (int j = 0; j < 8; j++) o.s[j] = f2bf(src[(size_t)j * DH_]);
    *reinterpret_cast<uint4*>(vt + ((size_t)bh * DH_ + d) * NC_ + (size_t)kc * 8) = o.u;
}

// ---------------- m97-style 128x128 GEMM core (C = A.B^T, K=1024) ----------------
static __device__ __forceinline__ void stage32(const unsigned short* g, unsigned short* lds,
                                               int w, int l) {
#pragma unroll
    for (int i = 0; i < 2; i++) {
        const unsigned short* gp = g + (size_t)(w * 32 + i * 16 + (l >> 2)) * C_ + (l & 3) * 8;
        unsigned short* lp = lds + (w * 32 + i * 16) * 32;   // wave-uniform
        gl_lds(gp, lp);
    }
}

static __device__ __forceinline__ void gemm_core(const unsigned short* Ag, const unsigned short* Bg,
                                                 unsigned short* As, unsigned short* Bs,
                                                 int w, int l, int wr, int wc, int quad, int col,
                                                 f32x4 acc[4][4]) {
    for (int kk = 0; kk < C_; kk += 32) {
        __syncthreads();
        stage32(Ag + kk, As, w, l);
        stage32(Bg + kk, Bs, w, l);
        __syncthreads();
        bf16x8 af[4], bfr[4];
#pragma unroll
        for (int t = 0; t < 4; t++) af[t]  = ldfrag(&As[(wr * 64 + t * 16 + col) * 32 + quad * 8]);
#pragma unroll
        for (int t = 0; t < 4; t++) bfr[t] = ldfrag(&Bs[(wc * 64 + t * 16 + col) * 32 + quad * 8]);
#pragma unroll
        for (int mt = 0; mt < 4; mt++)
#pragma unroll
            for (int nt = 0; nt < 4; nt++)
                acc[mt][nt] = __builtin_amdgcn_mfma_f32_16x16x32_bf16(af[mt], bfr[nt], acc[mt][nt], 0, 0, 0);
    }
}

// ---------------- QKV GEMM (4096x1024)x(3072x1024)^T + scatter epilogue ----------------
__global__ __launch_bounds__(256) void qkv_gemm_kernel(
    const unsigned short* __restrict__ xbf,
    const unsigned short* __restrict__ wbf,
    const float* __restrict__ bias,
    const int* __restrict__ uidx,
    unsigned short* __restrict__ qb,   // (B,H,NX,DH) scaled by 0.125*log2(e)
    unsigned short* __restrict__ kf,   // (B,H,NC,DH)
    unsigned short* __restrict__ vt)   // (B,H,DH,NC)
{
    __shared__ unsigned short As[128 * 32], Bs[128 * 32];
    int bn = blockIdx.x, bm = blockIdx.y;
    int w = threadIdx.x >> 6, l = threadIdx.x & 63;
    int quad = l >> 4, col = l & 15;
    int wr = w >> 1, wc = w & 1;
    f32x4 acc[4][4];
#pragma unroll
    for (int a = 0; a < 4; a++)
#pragma unroll
        for (int b = 0; b < 4; b++) acc[a][b] = (f32x4){0.f, 0.f, 0.f, 0.f};

    gemm_core(xbf + (size_t)(bm * 128) * C_, wbf + (size_t)(bn * 128) * C_,
              As, Bs, w, l, wr, wc, quad, col, acc);

    int part = bn >> 3;             // 0=q 1=k 2=v
    float bv[4]; int nl[4];
#pragma unroll
    for (int nt = 0; nt < 4; nt++) {
        int n = bn * 128 + wc * 64 + nt * 16 + col;
        bv[nt] = bias[n];
        nl[nt] = n & 1023;
    }
    const float QS = 0.18033688011112042f;   // 0.125 * log2(e)
#pragma unroll
    for (int mt = 0; mt < 4; mt++)
#pragma unroll
        for (int r = 0; r < 4; r++) {
            int m = bm * 128 + wr * 64 + mt * 16 + quad * 4 + r;
            int b = m >> 10, i = m & 1023;
            int j = (part == 0) ? 0 : uidx[(b << 10) + i];
#pragma unroll
            for (int nt = 0; nt < 4; nt++) {
                int h = nl[nt] >> 6, d = nl[nt] & 63;
                float v = acc[mt][nt][r] + bv[nt];
                if (part == 0)
                    qb[((size_t)(b * H_ + h) * NX_ + i) * DH_ + d] = f2bf(v * QS);
                else if (part == 1)
                    kf[((size_t)(b * H_ + h) * NC_ + j) * DH_ + d] = f2bf(v);
                else
                    vt[((size_t)(b * H_ + h) * DH_ + d) * NC_ + j] = f2bf(v);
            }
        }
}

// ---------------- flash attention: LDS-staged K/V tiles, no-max softmax ----------------
// The R1-R6 ~240us wall was the 16-line-gather per K/V fragment load (each
// global_load_dwordx4 touched 16 distinct cache lines, x4 waves redundantly).
// Now: per 64-key tile, K (8KB) and V^T (8KB) are staged into LDS with 16
// coalesced 1KB global_load_lds instrs (4/wave), shared by all 4 waves.
// LDS layout = m97-style [64 rows][32 shorts] half-tiles so fragment reads
// are the GEMM-proven ds_read_b128 row*64B+quad*16B pattern.
// XCD swizzle (id%8==bh%8) keeps the working set L2-resident (R6: 21MB fetch).
#define PST 40   // P row stride (32 keys + 8 pad) ushorts
__global__ __launch_bounds__(256, 4) void attn_kernel(
    const unsigned short* __restrict__ qb,
    const unsigned short* __restrict__ kf,
    const unsigned short* __restrict__ vt,
    unsigned short* __restrict__ ao)          // (B,NX,C) bf16
{
    __shared__ unsigned short Klo[64 * 32], Khi[64 * 32];   // K tile: dh 0-31 / 32-63
    __shared__ unsigned short V0s[64 * 32], V1s[64 * 32];   // V^T tile: keys 0-31 / 32-63
    __shared__ unsigned short Psh[4][16 * PST];             // 5 KB; total LDS 21.25 KB
    int id = blockIdx.x;
    int qt = (id >> 3) & 15;               // 0..15
    int bh = ((id >> 7) << 3) | (id & 7);  // 0..63, id%8 == bh%8
    int wave = threadIdx.x >> 6, lane = threadIdx.x & 63;
    int quad = lane >> 4, col = lane & 15;
    int srow = lane >> 2, schk = lane & 3; // staging: 16 rows x 4 chunks(16B)

    const unsigned short* qrow = qb + ((size_t)bh * NX_ + qt * 64 + wave * 16 + col) * DH_;
    bf16x8 qf0 = ldfrag(qrow + quad * 8);
    bf16x8 qf1 = ldfrag(qrow + 32 + quad * 8);

    const unsigned short* kbase = kf + (size_t)bh * NC_ * DH_;
    const unsigned short* vbase = vt + (size_t)bh * DH_ * NC_;
    unsigned short* Pw = &Psh[wave][0];

    f32x4 o[4];
#pragma unroll
    for (int t = 0; t < 4; t++) o[t] = (f32x4){0.f, 0.f, 0.f, 0.f};
    float l_i = 0.f;

    for (int kb = 0; kb < 32; kb++) {
        __syncthreads();   // all waves done reading previous tile
        {
            // K: rows = keys (contiguous 128B rows); wave stages keys [wave*16,+16)
            const unsigned short* Kt = kbase + (size_t)(kb * 64 + wave * 16 + srow) * DH_;
            gl_lds(Kt +      schk * 8, Klo + wave * 16 * 32);
            gl_lds(Kt + 32 + schk * 8, Khi + wave * 16 * 32);
            // V^T: rows = dh (stride NC_); wave stages d-rows [wave*16,+16)
            const unsigned short* Vt = vbase + (size_t)(wave * 16 + srow) * NC_ + kb * 64;
            gl_lds(Vt +      schk * 8, V0s + wave * 16 * 32);
            gl_lds(Vt + 32 + schk * 8, V1s + wave * 16 * 32);
        }
        __syncthreads();   // vmcnt drained by compiler before barrier

#pragma unroll
        for (int ks = 0; ks < 2; ks++) {
            // ---- S^T = K.Q^T over 32 keys ----
            f32x4 s0 = (f32x4){0.f, 0.f, 0.f, 0.f};
            f32x4 s1 = (f32x4){0.f, 0.f, 0.f, 0.f};
            {
                bf16x8 a0 = ldfrag(&Klo[(ks * 32 +      col) * 32 + quad * 8]);
                bf16x8 b0 = ldfrag(&Khi[(ks * 32 +      col) * 32 + quad * 8]);
                bf16x8 a1 = ldfrag(&Klo[(ks * 32 + 16 + col) * 32 + quad * 8]);
                bf16x8 b1 = ldfrag(&Khi[(ks * 32 + 16 + col) * 32 + quad * 8]);
                s0 = __builtin_amdgcn_mfma_f32_16x16x32_bf16(a0, qf0, s0, 0, 0, 0);
                s0 = __builtin_amdgcn_mfma_f32_16x16x32_bf16(b0, qf1, s0, 0, 0, 0);
                s1 = __builtin_amdgcn_mfma_f32_16x16x32_bf16(a1, qf0, s1, 0, 0, 0);
                s1 = __builtin_amdgcn_mfma_f32_16x16x32_bf16(b1, qf1, s1, 0, 0, 0);
            }
            // ---- V fragments (LDS, issued before softmax to overlap) ----
            const unsigned short* Vs = (ks == 0) ? V0s : V1s;
            bf16x8 vfr[4];
#pragma unroll
            for (int t = 0; t < 4; t++) vfr[t] = ldfrag(&Vs[(t * 16 + col) * 32 + quad * 8]);
            // ---- no-max softmax (log2 domain; Q pre-scaled by 0.125*log2e) ----
            {
                float p0 = exp2f(s0[0]), p1 = exp2f(s0[1]), p2 = exp2f(s0[2]), p3 = exp2f(s0[3]);
                float p4 = exp2f(s1[0]), p5 = exp2f(s1[1]), p6 = exp2f(s1[2]), p7 = exp2f(s1[3]);
                l_i += ((p0 + p1) + (p2 + p3)) + ((p4 + p5) + (p6 + p7));
                uint2 w0; w0.x = pk2(p0, p1); w0.y = pk2(p2, p3);
                uint2 w1; w1.x = pk2(p4, p5); w1.y = pk2(p6, p7);
                *reinterpret_cast<uint2*>(&Pw[col * PST +      quad * 4]) = w0;
                *reinterpret_cast<uint2*>(&Pw[col * PST + 16 + quad * 4]) = w1;
            }
            asm volatile("" ::: "memory");   // P writes before P read (in-wave LDS in-order)
            // ---- O^T += V^T . P^T ----
            {
                bf16x8 pf = ldfrag(&Pw[col * PST + quad * 8]);
#pragma unroll
                for (int t = 0; t < 4; t++)
                    o[t] = __builtin_amdgcn_mfma_f32_16x16x32_bf16(vfr[t], pf, o[t], 0, 0, 0);
            }
            asm volatile("" ::: "memory");   // P read done before next subiter's writes
        }
    }

    // ---- l across quads (same query = same col) ----
    l_i += __shfl_xor(l_i, 16, 64);
    l_i += __shfl_xor(l_i, 32, 64);
    float inv = 1.f / l_i;

    int b = bh >> 4, h = bh & 15;
    int q = qt * 64 + wave * 16 + col;
    unsigned short* orow = ao + ((size_t)b * NX_ + q) * C_ + h * 64;
#pragma unroll
    for (int t = 0; t < 4; t++) {
        uint2 ov;
        ov.x = pk2(o[t][0] * inv, o[t][1] * inv);
        ov.y = pk2(o[t][2] * inv, o[t][3] * inv);
        *reinterpret_cast<uint2*>(&orow[t * 16 + quad * 4]) = ov;
    }
}

// ---------------- projection GEMM (4096x1024)x(1024x1024)^T + bias ----------------
__global__ __launch_bounds__(256) void proj_gemm_kernel(
    const unsigned short* __restrict__ abf,
    const unsigned short* __restrict__ wbf,
    const float* __restrict__ bias,
    float* __restrict__ out)
{
    __shared__ unsigned short As[128 * 32], Bs[128 * 32];
    int bn = blockIdx.x, bm = blockIdx.y;
    int w = threadIdx.x >> 6, l = threadIdx.x & 63;
    int quad = l >> 4, col = l & 15;
    int wr = w >> 1, wc = w & 1;
    f32x4 acc[4][4];
#pragma unroll
    for (int a = 0; a < 4; a++)
#pragma unroll
        for (int b = 0; b < 4; b++) acc[a][b] = (f32x4){0.f, 0.f, 0.f, 0.f};

    gemm_core(abf + (size_t)(bm * 128) * C_, wbf + (size_t)(bn * 128) * C_,
              As, Bs, w, l, wr, wc, quad, col, acc);

    float bv[4];
#pragma unroll
    for (int nt = 0; nt < 4; nt++) bv[nt] = bias[bn * 128 + wc * 64 + nt * 16 + col];
#pragma unroll
    for (int mt = 0; mt < 4; mt++)
#pragma unroll
        for (int r = 0; r < 4; r++) {
            int m = bm * 128 + wr * 64 + mt * 16 + quad * 4 + r;
#pragma unroll
            for (int nt = 0; nt < 4; nt++) {
                int n = bn * 128 + wc * 64 + nt * 16 + col;
                out[(size_t)m * C_ + n] = acc[mt][nt][r] + bv[nt];
            }
        }
}

extern "C" void kernel_launch(void* const* d_in, const int* in_sizes, int n_in,
                              void* d_out, int out_size, void* d_ws, size_t ws_size,
                              hipStream_t stream) {
    const float* x      = (const float*)d_in[0];
    const int*   uidx   = (const int*)  d_in[1];
    const float* cachek = (const float*)d_in[2];
    const float* cachev = (const float*)d_in[3];
    const float* wqkv   = (const float*)d_in[4];
    const float* bqkv   = (const float*)d_in[5];
    const float* wproj  = (const float*)d_in[6];
    const float* bproj  = (const float*)d_in[7];
    float* out = (float*)d_out;

    char* ws = (char*)d_ws;
    unsigned short* xbf  = (unsigned short*)(ws);                       // 8 MB
    unsigned short* wqbf = (unsigned short*)(ws + (8ull  << 20));       // 6 MB
    unsigned short* wpbf = (unsigned short*)(ws + (14ull << 20));       // 2 MB
    unsigned short* qb   = (unsigned short*)(ws + (16ull << 20));       // 8 MB
    unsigned short* kfb  = (unsigned short*)(ws + (24ull << 20));       // 16 MB
    unsigned short* vtb  = (unsigned short*)(ws + (40ull << 20));       // 16 MB
    unsigned short* aob  = (unsigned short*)(ws + (56ull << 20));       // 8 MB

    cvt_all_kernel<<<16384, 256, 0, stream>>>(x, wqkv, wproj, cachek, xbf, wqbf, wpbf, kfb);
    vt_cvt_kernel <<<4096, 256, 0, stream>>>(cachev, vtb);

    qkv_gemm_kernel <<<dim3(24, 32), 256, 0, stream>>>(xbf, wqbf, bqkv, uidx, qb, kfb, vtb);
    attn_kernel     <<<1024, 256, 0, stream>>>(qb, kfb, vtb, aob);
    proj_gemm_kernel<<<dim3(8, 32),  256, 0, stream>>>(aob, wpbf, bproj, out);
}

// Round 8
// 272.157 us; speedup vs baseline: 2.0523x; 1.0377x over previous
//
#include <hip/hip_runtime.h>
#include <hip/hip_bf16.h>

#define B_   4
#define NX_  1024
#define NC_  2048
#define C_   1024
#define H_   16
#define DH_  64

typedef __attribute__((ext_vector_type(8))) __bf16 bf16x8;
typedef __attribute__((ext_vector_type(4))) float  f32x4;

// RNE float->bf16 (inputs finite)
static __device__ __forceinline__ unsigned short f2bf(float f) {
    unsigned int u = __float_as_uint(f);
    u += 0x7fffu + ((u >> 16) & 1u);
    return (unsigned short)(u >> 16);
}

// pack 2 floats -> 2 bf16 (round-half-up)
static __device__ __forceinline__ unsigned int pk2(float lo, float hi) {
    unsigned int a = __float_as_uint(lo) + 0x8000u;
    unsigned int b = __float_as_uint(hi) + 0x8000u;
    return __builtin_amdgcn_perm(b, a, 0x07060302);   // {b.hi16, a.hi16}
}

static __device__ __forceinline__ bf16x8 ldfrag(const unsigned short* p) {
    union { uint4 u; bf16x8 b; } cv;
    cv.u = *reinterpret_cast<const uint4*>(p);
    return cv.b;
}

// ---------------- merged converts: x, w_qkv, w_proj, cache_k (flat) + cache_v (transpose) ----------------
__global__ __launch_bounds__(256) void cvt_all_kernel(
    const float* __restrict__ x,  const float* __restrict__ wq,
    const float* __restrict__ wp, const float* __restrict__ ck,
    const float* __restrict__ cv_,
    unsigned short* __restrict__ xbf,  unsigned short* __restrict__ wqbf,
    unsigned short* __restrict__ wpbf, unsigned short* __restrict__ kfb,
    unsigned short* __restrict__ vt) {
    int blk = blockIdx.x;
    if (blk < 16384) {
        const float* src; unsigned short* dst; int i;
        if (blk < 4096)      { src = x;  dst = xbf;  i = blk; }
        else if (blk < 7168) { src = wq; dst = wqbf; i = blk - 4096; }
        else if (blk < 8192) { src = wp; dst = wpbf; i = blk - 7168; }
        else                 { src = ck; dst = kfb;  i = blk - 8192; }
        int idx = i * 256 + threadIdx.x;
        float4 f = reinterpret_cast<const float4*>(src)[idx];
        ushort4 o;
        o.x = f2bf(f.x); o.y = f2bf(f.y); o.z = f2bf(f.z); o.w = f2bf(f.w);
        reinterpret_cast<ushort4*>(dst)[idx] = o;
    } else {
        int i   = blk - 16384;       // 0..4095
        int t   = threadIdx.x;
        int bh  = i >> 6;
        int kg  = i & 63;
        int d   = t & 63;
        int kci = t >> 6;
        int kc  = kg * 4 + kci;
        const float* src = cv_ + ((size_t)bh * NC_ + (size_t)kc * 8) * DH_ + d;
        union { uint4 u; unsigned short s[8]; } o;
#pragma unroll
        for (int j = 0; j < 8; j++) o.s[j] = f2bf(src[(size_t)j * DH_]);
        *reinterpret_cast<uint4*>(vt + ((size_t)bh * DH_ + d) * NC_ + (size_t)kc * 8) = o.u;
    }
}

// ======================= reg-staged padded-LDS GEMM cores =======================
// LDS rows padded to 40 shorts (80 B): row*20 mod 32 -> 2-way bank alias = free.
// Tiles staged global->VGPR one full K-step ahead, then ds_write after barrier:
// the pre-barrier vmcnt wait is on year-old loads -> no exposed latency.
#define LSTR 40

// ---------------- QKV GEMM (4096x1024)x(3072x1024)^T, 128x128 tile + scatter ----------------
__global__ __launch_bounds__(256, 3) void qkv_gemm_kernel(
    const unsigned short* __restrict__ xbf,
    const unsigned short* __restrict__ wbf,
    const float* __restrict__ bias,
    const int* __restrict__ uidx,
    unsigned short* __restrict__ qb,   // (B,H,NX,DH) scaled by 0.125*log2(e)
    unsigned short* __restrict__ kf,   // (B,H,NC,DH)
    unsigned short* __restrict__ vt)   // (B,H,DH,NC)
{
    __shared__ unsigned short As[128 * LSTR], Bs[128 * LSTR];
    int bn = blockIdx.x, bm = blockIdx.y;
    int w = threadIdx.x >> 6, l = threadIdx.x & 63;
    int quad = l >> 4, col = l & 15;
    int wr = w >> 1, wc = w & 1;
    int srow = w * 32 + (l >> 2), schk = (l & 3) * 8;   // staging: 32 rows/wave x 4 chunks

    const unsigned short* Ap = xbf + (size_t)(bm * 128 + srow) * C_ + schk;
    const unsigned short* Bp = wbf + (size_t)(bn * 128 + srow) * C_ + schk;
    unsigned short* Aw = As + srow * LSTR + schk;
    unsigned short* Bw = Bs + srow * LSTR + schk;

    f32x4 acc[4][4];
#pragma unroll
    for (int a = 0; a < 4; a++)
#pragma unroll
        for (int b = 0; b < 4; b++) acc[a][b] = (f32x4){0.f, 0.f, 0.f, 0.f};

    uint4 ar0, ar1, br0, br1;
#define LDREG(kk_)                                                       \
    {   int kk = (kk_) * 32;                                             \
        ar0 = *reinterpret_cast<const uint4*>(Ap + kk);                  \
        ar1 = *reinterpret_cast<const uint4*>(Ap + 16 * C_ + kk);        \
        br0 = *reinterpret_cast<const uint4*>(Bp + kk);                  \
        br1 = *reinterpret_cast<const uint4*>(Bp + 16 * C_ + kk);        \
    }
#define WRTILE()                                                         \
    {   *reinterpret_cast<uint4*>(Aw)             = ar0;                 \
        *reinterpret_cast<uint4*>(Aw + 16 * LSTR) = ar1;                 \
        *reinterpret_cast<uint4*>(Bw)             = br0;                 \
        *reinterpret_cast<uint4*>(Bw + 16 * LSTR) = br1;                 \
    }

    LDREG(0);
    WRTILE();
    LDREG(1);
    __syncthreads();
#pragma unroll 1
    for (int it = 0; it < 32; it++) {
        bf16x8 af[4], bfr[4];
#pragma unroll
        for (int t = 0; t < 4; t++) af[t]  = ldfrag(&As[(wr * 64 + t * 16 + col) * LSTR + quad * 8]);
#pragma unroll
        for (int t = 0; t < 4; t++) bfr[t] = ldfrag(&Bs[(wc * 64 + t * 16 + col) * LSTR + quad * 8]);
#pragma unroll
        for (int mt = 0; mt < 4; mt++)
#pragma unroll
            for (int nt = 0; nt < 4; nt++)
                acc[mt][nt] = __builtin_amdgcn_mfma_f32_16x16x32_bf16(af[mt], bfr[nt], acc[mt][nt], 0, 0, 0);
        if (it < 31) {
            __syncthreads();
            WRTILE();
            LDREG(it + 2 < 31 ? it + 2 : 31);
            __syncthreads();
        }
    }
#undef LDREG
#undef WRTILE

    int part = bn >> 3;             // 0=q 1=k 2=v
    float bv[4]; int nl[4];
#pragma unroll
    for (int nt = 0; nt < 4; nt++) {
        int n = bn * 128 + wc * 64 + nt * 16 + col;
        bv[nt] = bias[n];
        nl[nt] = n & 1023;
    }
    const float QS = 0.18033688011112042f;   // 0.125 * log2(e)
#pragma unroll
    for (int mt = 0; mt < 4; mt++)
#pragma unroll
        for (int r = 0; r < 4; r++) {
            int m = bm * 128 + wr * 64 + mt * 16 + quad * 4 + r;
            int b = m >> 10, i = m & 1023;
            int j = (part == 0) ? 0 : uidx[(b << 10) + i];
#pragma unroll
            for (int nt = 0; nt < 4; nt++) {
                int h = nl[nt] >> 6, d = nl[nt] & 63;
                float v = acc[mt][nt][r] + bv[nt];
                if (part == 0)
                    qb[((size_t)(b * H_ + h) * NX_ + i) * DH_ + d] = f2bf(v * QS);
                else if (part == 1)
                    kf[((size_t)(b * H_ + h) * NC_ + j) * DH_ + d] = f2bf(v);
                else
                    vt[((size_t)(b * H_ + h) * DH_ + d) * NC_ + j] = f2bf(v);
            }
        }
}

// ---------------- flash attention: reg-staged padded K/V tiles, no-max softmax ----------------
// R7's residual: 8-way bank conflicts (64B LDS rows forced by global_load_lds;
// 11.5M conflict-cycles) + per-tile exposed load latency (loads issued right
// before the barrier). Now: tiles go global->VGPR one tile ahead, ds_write to
// 80B-strided rows (2-way alias = free), barrier waits on long-arrived data.
#define PST 40
__global__ __launch_bounds__(256, 4) void attn_kernel(
    const unsigned short* __restrict__ qb,
    const unsigned short* __restrict__ kf,
    const unsigned short* __restrict__ vt,
    unsigned short* __restrict__ ao)          // (B,NX,C) bf16
{
    __shared__ unsigned short Klo[64 * LSTR], Khi[64 * LSTR];   // K tile: dh 0-31 / 32-63
    __shared__ unsigned short V0s[64 * LSTR], V1s[64 * LSTR];   // V^T tile: keys 0-31 / 32-63
    __shared__ unsigned short Psh[4][16 * PST];                 // 25.6 KB total
    int id = blockIdx.x;
    int qt = (id >> 3) & 15;               // 0..15
    int bh = ((id >> 7) << 3) | (id & 7);  // 0..63, id%8 == bh%8 (XCD locality)
    int wave = threadIdx.x >> 6, lane = threadIdx.x & 63;
    int quad = lane >> 4, col = lane & 15;
    int srow = wave * 16 + (lane >> 2), schk = (lane & 3) * 8;  // staging: 16 rows/wave

    const unsigned short* qrow = qb + ((size_t)bh * NX_ + qt * 64 + wave * 16 + col) * DH_;
    bf16x8 qf0 = ldfrag(qrow + quad * 8);
    bf16x8 qf1 = ldfrag(qrow + 32 + quad * 8);

    const unsigned short* Kp = kf + ((size_t)bh * NC_ + srow) * DH_ + schk;       // + kb*64*DH_
    const unsigned short* Vp = vt + ((size_t)bh * DH_ + srow) * NC_ + schk;       // + kb*64
    unsigned short* Kwl = Klo + srow * LSTR + schk;
    unsigned short* Kwh = Khi + srow * LSTR + schk;
    unsigned short* Vw0 = V0s + srow * LSTR + schk;
    unsigned short* Vw1 = V1s + srow * LSTR + schk;
    unsigned short* Pw = &Psh[wave][0];

    f32x4 o[4];
#pragma unroll
    for (int t = 0; t < 4; t++) o[t] = (f32x4){0.f, 0.f, 0.f, 0.f};
    float l_i = 0.f;

    uint4 kr0, kr1, vr0, vr1;
#define LDREG(kb_)                                                        \
    {   kr0 = *reinterpret_cast<const uint4*>(Kp + (size_t)(kb_) * 64 * DH_);      \
        kr1 = *reinterpret_cast<const uint4*>(Kp + (size_t)(kb_) * 64 * DH_ + 32); \
        vr0 = *reinterpret_cast<const uint4*>(Vp + (kb_) * 64);           \
        vr1 = *reinterpret_cast<const uint4*>(Vp + (kb_) * 64 + 32);      \
    }
#define WRTILE()                                                          \
    {   *reinterpret_cast<uint4*>(Kwl) = kr0;                             \
        *reinterpret_cast<uint4*>(Kwh) = kr1;                             \
        *reinterpret_cast<uint4*>(Vw0) = vr0;                             \
        *reinterpret_cast<uint4*>(Vw1) = vr1;                             \
    }

    LDREG(0);
    WRTILE();
    LDREG(1);
    __syncthreads();

#pragma unroll 1
    for (int kb = 0; kb < 32; kb++) {
#pragma unroll
        for (int ks = 0; ks < 2; ks++) {
            // ---- S^T = K.Q^T over 32 keys ----
            f32x4 s0 = (f32x4){0.f, 0.f, 0.f, 0.f};
            f32x4 s1 = (f32x4){0.f, 0.f, 0.f, 0.f};
            {
                bf16x8 a0 = ldfrag(&Klo[(ks * 32 +      col) * LSTR + quad * 8]);
                bf16x8 b0 = ldfrag(&Khi[(ks * 32 +      col) * LSTR + quad * 8]);
                bf16x8 a1 = ldfrag(&Klo[(ks * 32 + 16 + col) * LSTR + quad * 8]);
                bf16x8 b1 = ldfrag(&Khi[(ks * 32 + 16 + col) * LSTR + quad * 8]);
                s0 = __builtin_amdgcn_mfma_f32_16x16x32_bf16(a0, qf0, s0, 0, 0, 0);
                s0 = __builtin_amdgcn_mfma_f32_16x16x32_bf16(b0, qf1, s0, 0, 0, 0);
                s1 = __builtin_amdgcn_mfma_f32_16x16x32_bf16(a1, qf0, s1, 0, 0, 0);
                s1 = __builtin_amdgcn_mfma_f32_16x16x32_bf16(b1, qf1, s1, 0, 0, 0);
            }
            const unsigned short* Vs = (ks == 0) ? V0s : V1s;
            bf16x8 vfr[4];
#pragma unroll
            for (int t = 0; t < 4; t++) vfr[t] = ldfrag(&Vs[(t * 16 + col) * LSTR + quad * 8]);
            // ---- no-max softmax (log2 domain; Q pre-scaled by 0.125*log2e) ----
            {
                float p0 = exp2f(s0[0]), p1 = exp2f(s0[1]), p2 = exp2f(s0[2]), p3 = exp2f(s0[3]);
                float p4 = exp2f(s1[0]), p5 = exp2f(s1[1]), p6 = exp2f(s1[2]), p7 = exp2f(s1[3]);
                l_i += ((p0 + p1) + (p2 + p3)) + ((p4 + p5) + (p6 + p7));
                uint2 w0; w0.x = pk2(p0, p1); w0.y = pk2(p2, p3);
                uint2 w1; w1.x = pk2(p4, p5); w1.y = pk2(p6, p7);
                *reinterpret_cast<uint2*>(&Pw[col * PST +      quad * 4]) = w0;
                *reinterpret_cast<uint2*>(&Pw[col * PST + 16 + quad * 4]) = w1;
            }
            asm volatile("" ::: "memory");   // P writes before P read (in-wave LDS in-order)
            {
                bf16x8 pf = ldfrag(&Pw[col * PST + quad * 8]);
#pragma unroll
                for (int t = 0; t < 4; t++)
                    o[t] = __builtin_amdgcn_mfma_f32_16x16x32_bf16(vfr[t], pf, o[t], 0, 0, 0);
            }
            asm volatile("" ::: "memory");   // P read done before next subiter's writes
        }
        if (kb < 31) {
            __syncthreads();                 // all waves done reading tile kb
            WRTILE();                        // tile kb+1 (regs arrived a tile ago)
            LDREG(kb + 2 < 31 ? kb + 2 : 31);
            __syncthreads();                 // tile kb+1 visible
        }
    }
#undef LDREG
#undef WRTILE

    // ---- l across quads (same query = same col) ----
    l_i += __shfl_xor(l_i, 16, 64);
    l_i += __shfl_xor(l_i, 32, 64);
    float inv = 1.f / l_i;

    int b = bh >> 4, h = bh & 15;
    int q = qt * 64 + wave * 16 + col;
    unsigned short* orow = ao + ((size_t)b * NX_ + q) * C_ + h * 64;
#pragma unroll
    for (int t = 0; t < 4; t++) {
        uint2 ov;
        ov.x = pk2(o[t][0] * inv, o[t][1] * inv);
        ov.y = pk2(o[t][2] * inv, o[t][3] * inv);
        *reinterpret_cast<uint2*>(&orow[t * 16 + quad * 4]) = ov;
    }
}

// ---------------- projection GEMM (4096x1024)x(1024x1024)^T, 128x64 tile ----------------
// grid (16,32) = 512 blocks = 2/CU (vs 1/CU at 128x128). Wave owns 32 rows x 64 cols.
__global__ __launch_bounds__(256, 3) void proj_gemm_kernel(
    const unsigned short* __restrict__ abf,
    const unsigned short* __restrict__ wbf,
    const float* __restrict__ bias,
    float* __restrict__ out)
{
    __shared__ unsigned short As[128 * LSTR], Bs[64 * LSTR];
    int bn = blockIdx.x, bm = blockIdx.y;
    int w = threadIdx.x >> 6, l = threadIdx.x & 63;
    int quad = l >> 4, col = l & 15;
    int sarow = w * 32 + (l >> 2), sbrow = w * 16 + (l >> 2), schk = (l & 3) * 8;

    const unsigned short* Ap = abf + (size_t)(bm * 128 + sarow) * C_ + schk;
    const unsigned short* Bp = wbf + (size_t)(bn * 64 + sbrow) * C_ + schk;
    unsigned short* Aw = As + sarow * LSTR + schk;
    unsigned short* Bw = Bs + sbrow * LSTR + schk;

    f32x4 acc[2][4];
#pragma unroll
    for (int a = 0; a < 2; a++)
#pragma unroll
        for (int b = 0; b < 4; b++) acc[a][b] = (f32x4){0.f, 0.f, 0.f, 0.f};

    uint4 ar0, ar1, br0;
#define LDREG(kk_)                                                       \
    {   int kk = (kk_) * 32;                                             \
        ar0 = *reinterpret_cast<const uint4*>(Ap + kk);                  \
        ar1 = *reinterpret_cast<const uint4*>(Ap + 16 * C_ + kk);        \
        br0 = *reinterpret_cast<const uint4*>(Bp + kk);                  \
    }
#define WRTILE()                                                         \
    {   *reinterpret_cast<uint4*>(Aw)             = ar0;                 \
        *reinterpret_cast<uint4*>(Aw + 16 * LSTR) = ar1;                 \
        *reinterpret_cast<uint4*>(Bw)             = br0;                 \
    }

    LDREG(0);
    WRTILE();
    LDREG(1);
    __syncthreads();
#pragma unroll 1
    for (int it = 0; it < 32; it++) {
        bf16x8 af[2], bfr[4];
#pragma unroll
        for (int t = 0; t < 2; t++) af[t]  = ldfrag(&As[(w * 32 + t * 16 + col) * LSTR + quad * 8]);
#pragma unroll
        for (int t = 0; t < 4; t++) bfr[t] = ldfrag(&Bs[(t * 16 + col) * LSTR + quad * 8]);
#pragma unroll
        for (int mt = 0; mt < 2; mt++)
#pragma unroll
            for (int nt = 0; nt < 4; nt++)
                acc[mt][nt] = __builtin_amdgcn_mfma_f32_16x16x32_bf16(af[mt], bfr[nt], acc[mt][nt], 0, 0, 0);
        if (it < 31) {
            __syncthreads();
            WRTILE();
            LDREG(it + 2 < 31 ? it + 2 : 31);
            __syncthreads();
        }
    }
#undef LDREG
#undef WRTILE

    float bv[4];
#pragma unroll
    for (int nt = 0; nt < 4; nt++) bv[nt] = bias[bn * 64 + nt * 16 + col];
#pragma unroll
    for (int mt = 0; mt < 2; mt++)
#pragma unroll
        for (int r = 0; r < 4; r++) {
            int m = bm * 128 + w * 32 + mt * 16 + quad * 4 + r;
#pragma unroll
            for (int nt = 0; nt < 4; nt++) {
                int n = bn * 64 + nt * 16 + col;
                out[(size_t)m * C_ + n] = acc[mt][nt][r] + bv[nt];
            }
        }
}

extern "C" void kernel_launch(void* const* d_in, const int* in_sizes, int n_in,
                              void* d_out, int out_size, void* d_ws, size_t ws_size,
                              hipStream_t stream) {
    const float* x      = (const float*)d_in[0];
    const int*   uidx   = (const int*)  d_in[1];
    const float* cachek = (const float*)d_in[2];
    const float* cachev = (const float*)d_in[3];
    const float* wqkv   = (const float*)d_in[4];
    const float* bqkv   = (const float*)d_in[5];
    const float* wproj  = (const float*)d_in[6];
    const float* bproj  = (const float*)d_in[7];
    float* out = (float*)d_out;

    char* ws = (char*)d_ws;
    unsigned short* xbf  = (unsigned short*)(ws);                       // 8 MB
    unsigned short* wqbf = (unsigned short*)(ws + (8ull  << 20));       // 6 MB
    unsigned short* wpbf = (unsigned short*)(ws + (14ull << 20));       // 2 MB
    unsigned short* qb   = (unsigned short*)(ws + (16ull << 20));       // 8 MB
    unsigned short* kfb  = (unsigned short*)(ws + (24ull << 20));       // 16 MB
    unsigned short* vtb  = (unsigned short*)(ws + (40ull << 20));       // 16 MB
    unsigned short* aob  = (unsigned short*)(ws + (56ull << 20));       // 8 MB

    cvt_all_kernel<<<20480, 256, 0, stream>>>(x, wqkv, wproj, cachek, cachev,
                                              xbf, wqbf, wpbf, kfb, vtb);
    qkv_gemm_kernel <<<dim3(24, 32), 256, 0, stream>>>(xbf, wqbf, bqkv, uidx, qb, kfb, vtb);
    attn_kernel     <<<1024, 256, 0, stream>>>(qb, kfb, vtb, aob);
    proj_gemm_kernel<<<dim3(16, 32), 256, 0, stream>>>(aob, wpbf, bproj, out);
}

// Round 9
// 262.668 us; speedup vs baseline: 2.1265x; 1.0361x over previous
//
#include <hip/hip_runtime.h>
#include <hip/hip_bf16.h>

#define B_   4
#define NX_  1024
#define NC_  2048
#define C_   1024
#define H_   16
#define DH_  64

typedef __attribute__((ext_vector_type(8))) __bf16 bf16x8;
typedef __attribute__((ext_vector_type(4))) float  f32x4;

// RNE float->bf16 (inputs finite)
static __device__ __forceinline__ unsigned short f2bf(float f) {
    unsigned int u = __float_as_uint(f);
    u += 0x7fffu + ((u >> 16) & 1u);
    return (unsigned short)(u >> 16);
}

// pack 2 floats -> 2 bf16 (round-half-up)
static __device__ __forceinline__ unsigned int pk2(float lo, float hi) {
    unsigned int a = __float_as_uint(lo) + 0x8000u;
    unsigned int b = __float_as_uint(hi) + 0x8000u;
    return __builtin_amdgcn_perm(b, a, 0x07060302);   // {b.hi16, a.hi16}
}

static __device__ __forceinline__ bf16x8 ldfrag(const unsigned short* p) {
    union { uint4 u; bf16x8 b; } cv;
    cv.u = *reinterpret_cast<const uint4*>(p);
    return cv.b;
}

// ---------------- merged converts: x, w_qkv, w_proj, cache_k (flat) + cache_v (transpose) ----------------
__global__ __launch_bounds__(256) void cvt_all_kernel(
    const float* __restrict__ x,  const float* __restrict__ wq,
    const float* __restrict__ wp, const float* __restrict__ ck,
    const float* __restrict__ cv_,
    unsigned short* __restrict__ xbf,  unsigned short* __restrict__ wqbf,
    unsigned short* __restrict__ wpbf, unsigned short* __restrict__ kfb,
    unsigned short* __restrict__ vt) {
    int blk = blockIdx.x;
    if (blk < 16384) {
        const float* src; unsigned short* dst; int i;
        if (blk < 4096)      { src = x;  dst = xbf;  i = blk; }
        else if (blk < 7168) { src = wq; dst = wqbf; i = blk - 4096; }
        else if (blk < 8192) { src = wp; dst = wpbf; i = blk - 7168; }
        else                 { src = ck; dst = kfb;  i = blk - 8192; }
        int idx = i * 256 + threadIdx.x;
        float4 f = reinterpret_cast<const float4*>(src)[idx];
        ushort4 o;
        o.x = f2bf(f.x); o.y = f2bf(f.y); o.z = f2bf(f.z); o.w = f2bf(f.w);
        reinterpret_cast<ushort4*>(dst)[idx] = o;
    } else {
        int i   = blk - 16384;       // 0..4095
        int t   = threadIdx.x;
        int bh  = i >> 6;
        int kg  = i & 63;
        int d   = t & 63;
        int kci = t >> 6;
        int kc  = kg * 4 + kci;
        const float* src = cv_ + ((size_t)bh * NC_ + (size_t)kc * 8) * DH_ + d;
        union { uint4 u; unsigned short s[8]; } o;
#pragma unroll
        for (int j = 0; j < 8; j++) o.s[j] = f2bf(src[(size_t)j * DH_]);
        *reinterpret_cast<uint4*>(vt + ((size_t)bh * DH_ + d) * NC_ + (size_t)kc * 8) = o.u;
    }
}

#define LSTR 40

// ---------------- QKV GEMM (4096x1024)x(3072x1024)^T, 128x128 tile + scatter ----------------
// V-part epilogue transposes acc through LDS so scatter stores have lanes =
// 64 consecutive tokens for one d-row: sorted j's span ~256B -> ~4 cache
// lines per store instruction instead of 64 (L2 write-transaction wall fix).
__global__ __launch_bounds__(256, 3) void qkv_gemm_kernel(
    const unsigned short* __restrict__ xbf,
    const unsigned short* __restrict__ wbf,
    const float* __restrict__ bias,
    const int* __restrict__ uidx,
    unsigned short* __restrict__ qb,   // (B,H,NX,DH) scaled by 0.125*log2(e)
    unsigned short* __restrict__ kf,   // (B,H,NC,DH)
    unsigned short* __restrict__ vt)   // (B,H,DH,NC)
{
    __shared__ unsigned short As[128 * LSTR], Bs[128 * LSTR];
    __shared__ int jtab[128];
    int bn = blockIdx.x, bm = blockIdx.y;
    int w = threadIdx.x >> 6, l = threadIdx.x & 63;
    int quad = l >> 4, col = l & 15;
    int wr = w >> 1, wc = w & 1;
    int srow = w * 32 + (l >> 2), schk = (l & 3) * 8;

    const unsigned short* Ap = xbf + (size_t)(bm * 128 + srow) * C_ + schk;
    const unsigned short* Bp = wbf + (size_t)(bn * 128 + srow) * C_ + schk;
    unsigned short* Aw = As + srow * LSTR + schk;
    unsigned short* Bw = Bs + srow * LSTR + schk;

    f32x4 acc[4][4];
#pragma unroll
    for (int a = 0; a < 4; a++)
#pragma unroll
        for (int b = 0; b < 4; b++) acc[a][b] = (f32x4){0.f, 0.f, 0.f, 0.f};

    uint4 ar0, ar1, br0, br1;
#define LDREG(kk_)                                                       \
    {   int kk = (kk_) * 32;                                             \
        ar0 = *reinterpret_cast<const uint4*>(Ap + kk);                  \
        ar1 = *reinterpret_cast<const uint4*>(Ap + 16 * C_ + kk);        \
        br0 = *reinterpret_cast<const uint4*>(Bp + kk);                  \
        br1 = *reinterpret_cast<const uint4*>(Bp + 16 * C_ + kk);        \
    }
#define WRTILE()                                                         \
    {   *reinterpret_cast<uint4*>(Aw)             = ar0;                 \
        *reinterpret_cast<uint4*>(Aw + 16 * LSTR) = ar1;                 \
        *reinterpret_cast<uint4*>(Bw)             = br0;                 \
        *reinterpret_cast<uint4*>(Bw + 16 * LSTR) = br1;                 \
    }

    LDREG(0);
    WRTILE();
    LDREG(1);
    __syncthreads();
#pragma unroll 1
    for (int it = 0; it < 32; it++) {
        bf16x8 af[4], bfr[4];
#pragma unroll
        for (int t = 0; t < 4; t++) af[t]  = ldfrag(&As[(wr * 64 + t * 16 + col) * LSTR + quad * 8]);
#pragma unroll
        for (int t = 0; t < 4; t++) bfr[t] = ldfrag(&Bs[(wc * 64 + t * 16 + col) * LSTR + quad * 8]);
#pragma unroll
        for (int mt = 0; mt < 4; mt++)
#pragma unroll
            for (int nt = 0; nt < 4; nt++)
                acc[mt][nt] = __builtin_amdgcn_mfma_f32_16x16x32_bf16(af[mt], bfr[nt], acc[mt][nt], 0, 0, 0);
        if (it < 31) {
            __syncthreads();
            WRTILE();
            LDREG(it + 2 < 31 ? it + 2 : 31);
            __syncthreads();
        }
    }
#undef LDREG
#undef WRTILE

    int part = bn >> 3;             // 0=q 1=k 2=v
    float bv[4];
#pragma unroll
    for (int nt = 0; nt < 4; nt++) bv[nt] = bias[bn * 128 + wc * 64 + nt * 16 + col];

    if (part <= 1) {
        int nl[4];
#pragma unroll
        for (int nt = 0; nt < 4; nt++) nl[nt] = (bn * 128 + wc * 64 + nt * 16 + col) & 1023;
        const float QS = 0.18033688011112042f;   // 0.125 * log2(e)
#pragma unroll
        for (int mt = 0; mt < 4; mt++)
#pragma unroll
            for (int r = 0; r < 4; r++) {
                int m = bm * 128 + wr * 64 + mt * 16 + quad * 4 + r;
                int b = m >> 10, i = m & 1023;
                int j = (part == 0) ? 0 : uidx[m];
#pragma unroll
                for (int nt = 0; nt < 4; nt++) {
                    int h = nl[nt] >> 6, d = nl[nt] & 63;
                    float v = acc[mt][nt][r] + bv[nt];
                    if (part == 0)
                        qb[((size_t)(b * H_ + h) * NX_ + i) * DH_ + d] = f2bf(v * QS);
                    else
                        kf[((size_t)(b * H_ + h) * NC_ + j) * DH_ + d] = f2bf(v);
                }
            }
    } else {
        // ---- V-part: LDS transpose + token-major scatter ----
        if (threadIdx.x < 128) jtab[threadIdx.x] = uidx[bm * 128 + threadIdx.x];
        __syncthreads();   // jtab ready; As/Bs reads from main loop done
        int h = ((bn * 128 + wc * 64) & 1023) >> 6;   // const per wave (64-aligned)
        int b = (bm * 128) >> 10;
        unsigned short* T = (wc == 0) ? As : Bs;      // 64 x 72 bf16 (9216 B)
        int jv = jtab[wr * 64 + l];
        unsigned short* vb2 = vt + ((size_t)(b * H_ + h) * 64) * NC_ + jv;
#pragma unroll 1
        for (int round = 0; round < 2; round++) {
            if (wr == round) {
#pragma unroll
                for (int nt = 0; nt < 4; nt++)
#pragma unroll
                    for (int mt = 0; mt < 4; mt++) {
                        uint2 pk;
                        pk.x = pk2(acc[mt][nt][0] + bv[nt], acc[mt][nt][1] + bv[nt]);
                        pk.y = pk2(acc[mt][nt][2] + bv[nt], acc[mt][nt][3] + bv[nt]);
                        *reinterpret_cast<uint2*>(&T[(nt * 16 + col) * 72 + mt * 16 + quad * 4]) = pk;
                    }
                asm volatile("s_waitcnt lgkmcnt(0)" ::: "memory");
#pragma unroll 1
                for (int d = 0; d < 64; d++)
                    vb2[(size_t)d * NC_] = T[d * 72 + l];   // lanes = 64 sorted tokens
            }
            __syncthreads();
        }
    }
}

// ---------------- flash attention: 32q/wave (qh,kh wave split), LDS-staged tiles ----------------
// attn is LDS-BW-bound (R8 model: 16 waves/CU x 23KB/tile / 128B/cy ~= measured).
// Now each wave covers 32 queries x 32 keys per tile: K/V fragment reads serve
// 2x queries -> 16KB per wave-tile per 1024 qk (1.5x less LDS). Key-halves
// merge by plain (O,l) addition at the end (no-max softmax); merge buffers
// alias the tile LDS. 1024 blocks = 4/CU = 16 waves/CU kept.
#define PST 40
__global__ __launch_bounds__(256, 4) void attn_kernel(
    const unsigned short* __restrict__ qb,
    const unsigned short* __restrict__ kf,
    const unsigned short* __restrict__ vt,
    unsigned short* __restrict__ ao)          // (B,NX,C) bf16
{
    __shared__ __align__(16) char smem[20480 + 10240];
    unsigned short* Klo = (unsigned short*)smem;          // 64 x 40 (keys x dh0-31)
    unsigned short* Khi = Klo + 64 * LSTR;                // dh 32-63
    unsigned short* V0s = Khi + 64 * LSTR;                // V^T: dh x keys 0-31
    unsigned short* V1s = V0s + 64 * LSTR;                // keys 32-63
    unsigned short* Psh = (unsigned short*)(smem + 20480);// [wave][nt][16*PST]
    float* Om = (float*)smem;                             // aliases tiles after loop: [qh][32][64]
    float* Lm = Om + 2 * 32 * 64;                         // [qh][nt][16]

    int id = blockIdx.x;
    int qt = (id >> 3) & 15;               // 0..15
    int bh = ((id >> 7) << 3) | (id & 7);  // 0..63, id%8 == bh%8 (XCD locality)
    int wave = threadIdx.x >> 6, lane = threadIdx.x & 63;
    int quad = lane >> 4, col = lane & 15;
    int qh = wave & 1;                     // query half (32 q)
    int kh = wave >> 1;                    // key half of each 64-key tile
    int srow = wave * 16 + (lane >> 2), schk = (lane & 3) * 8;

    // Q fragments: 2 q-16-tiles x 2 dh-halves
    const unsigned short* qrow0 = qb + ((size_t)bh * NX_ + qt * 64 + qh * 32 + col) * DH_;
    bf16x8 qfA[2], qfB[2];
    qfA[0] = ldfrag(qrow0 + quad * 8);
    qfB[0] = ldfrag(qrow0 + 32 + quad * 8);
    qfA[1] = ldfrag(qrow0 + 16 * DH_ + quad * 8);
    qfB[1] = ldfrag(qrow0 + 16 * DH_ + 32 + quad * 8);

    const unsigned short* Kp = kf + ((size_t)bh * NC_ + srow) * DH_ + schk;
    const unsigned short* Vp = vt + ((size_t)bh * DH_ + srow) * NC_ + schk;
    unsigned short* Kwl = Klo + srow * LSTR + schk;
    unsigned short* Kwh = Khi + srow * LSTR + schk;
    unsigned short* Vw0 = V0s + srow * LSTR + schk;
    unsigned short* Vw1 = V1s + srow * LSTR + schk;
    unsigned short* Pw0 = Psh + (wave * 2 + 0) * 16 * PST;
    unsigned short* Pw1 = Psh + (wave * 2 + 1) * 16 * PST;
    const unsigned short* Vs = kh ? V1s : V0s;
    int kq = kh * 32;

    f32x4 o[4][2];
#pragma unroll
    for (int m = 0; m < 4; m++)
#pragma unroll
        for (int n = 0; n < 2; n++) o[m][n] = (f32x4){0.f, 0.f, 0.f, 0.f};
    float l_i[2] = {0.f, 0.f};

    uint4 kr0, kr1, vr0, vr1;
#define LDREG(kb_)                                                        \
    {   kr0 = *reinterpret_cast<const uint4*>(Kp + (size_t)(kb_) * 64 * DH_);      \
        kr1 = *reinterpret_cast<const uint4*>(Kp + (size_t)(kb_) * 64 * DH_ + 32); \
        vr0 = *reinterpret_cast<const uint4*>(Vp + (kb_) * 64);           \
        vr1 = *reinterpret_cast<const uint4*>(Vp + (kb_) * 64 + 32);      \
    }
#define WRTILE()                                                          \
    {   *reinterpret_cast<uint4*>(Kwl) = kr0;                             \
        *reinterpret_cast<uint4*>(Kwh) = kr1;                             \
        *reinterpret_cast<uint4*>(Vw0) = vr0;                             \
        *reinterpret_cast<uint4*>(Vw1) = vr1;                             \
    }

    LDREG(0);
    WRTILE();
    LDREG(1);
    __syncthreads();

#pragma unroll 1
    for (int kb = 0; kb < 32; kb++) {
        // ---- S^T = K.Q^T : 32 keys (kh half) x 32 queries ----
        f32x4 s[2][2];
#pragma unroll
        for (int mt = 0; mt < 2; mt++)
#pragma unroll
            for (int nt = 0; nt < 2; nt++) s[mt][nt] = (f32x4){0.f, 0.f, 0.f, 0.f};
#pragma unroll
        for (int mt = 0; mt < 2; mt++) {
            bf16x8 ka = ldfrag(&Klo[(kq + mt * 16 + col) * LSTR + quad * 8]);
            bf16x8 kb_ = ldfrag(&Khi[(kq + mt * 16 + col) * LSTR + quad * 8]);
#pragma unroll
            for (int nt = 0; nt < 2; nt++) {
                s[mt][nt] = __builtin_amdgcn_mfma_f32_16x16x32_bf16(ka,  qfA[nt], s[mt][nt], 0, 0, 0);
                s[mt][nt] = __builtin_amdgcn_mfma_f32_16x16x32_bf16(kb_, qfB[nt], s[mt][nt], 0, 0, 0);
            }
        }
        // ---- V fragments (issued early) ----
        bf16x8 vfr[4];
#pragma unroll
        for (int t = 0; t < 4; t++) vfr[t] = ldfrag(&Vs[(t * 16 + col) * LSTR + quad * 8]);
        // ---- no-max softmax (log2 domain) ----
#pragma unroll
        for (int nt = 0; nt < 2; nt++) {
            unsigned short* Pw = nt ? Pw1 : Pw0;
            float p0 = exp2f(s[0][nt][0]), p1 = exp2f(s[0][nt][1]);
            float p2 = exp2f(s[0][nt][2]), p3 = exp2f(s[0][nt][3]);
            float p4 = exp2f(s[1][nt][0]), p5 = exp2f(s[1][nt][1]);
            float p6 = exp2f(s[1][nt][2]), p7 = exp2f(s[1][nt][3]);
            l_i[nt] += ((p0 + p1) + (p2 + p3)) + ((p4 + p5) + (p6 + p7));
            uint2 w0; w0.x = pk2(p0, p1); w0.y = pk2(p2, p3);
            uint2 w1; w1.x = pk2(p4, p5); w1.y = pk2(p6, p7);
            *reinterpret_cast<uint2*>(&Pw[col * PST +      quad * 4]) = w0;
            *reinterpret_cast<uint2*>(&Pw[col * PST + 16 + quad * 4]) = w1;
        }
        asm volatile("" ::: "memory");   // P writes before P reads (in-wave LDS in-order)
        // ---- O^T += V^T . P^T ----
        {
            bf16x8 pf0 = ldfrag(&Pw0[col * PST + quad * 8]);
            bf16x8 pf1 = ldfrag(&Pw1[col * PST + quad * 8]);
#pragma unroll
            for (int mt = 0; mt < 4; mt++) {
                o[mt][0] = __builtin_amdgcn_mfma_f32_16x16x32_bf16(vfr[mt], pf0, o[mt][0], 0, 0, 0);
                o[mt][1] = __builtin_amdgcn_mfma_f32_16x16x32_bf16(vfr[mt], pf1, o[mt][1], 0, 0, 0);
            }
        }
        asm volatile("" ::: "memory");   // P reads done before next iter's writes
        if (kb < 31) {
            __syncthreads();
            WRTILE();
            LDREG(kb + 2 < 31 ? kb + 2 : 31);
            __syncthreads();
        }
    }
#undef LDREG
#undef WRTILE

    // ---- reduce l across quads (same query = same col) ----
#pragma unroll
    for (int nt = 0; nt < 2; nt++) {
        l_i[nt] += __shfl_xor(l_i[nt], 16, 64);
        l_i[nt] += __shfl_xor(l_i[nt], 32, 64);
    }

    // ---- merge key halves: plain (O,l) addition (m==0 softmax) ----
    __syncthreads();   // tile reads done; smem reused as Om/Lm
    if (kh == 1) {
#pragma unroll
        for (int mt = 0; mt < 4; mt++)
#pragma unroll
            for (int nt = 0; nt < 2; nt++)
#pragma unroll
                for (int r = 0; r < 4; r++)
                    Om[(qh * 32 + (mt * 2 + nt) * 4 + r) * 64 + lane] = o[mt][nt][r];
        if (quad == 0) {
            Lm[(qh * 2 + 0) * 16 + col] = l_i[0];
            Lm[(qh * 2 + 1) * 16 + col] = l_i[1];
        }
    }
    __syncthreads();
    if (kh == 0) {
        float inv[2];
#pragma unroll
        for (int nt = 0; nt < 2; nt++)
            inv[nt] = 1.f / (l_i[nt] + Lm[(qh * 2 + nt) * 16 + col]);
        int b = bh >> 4, h = bh & 15;
#pragma unroll
        for (int mt = 0; mt < 4; mt++)
#pragma unroll
            for (int nt = 0; nt < 2; nt++) {
                int base = (qh * 32 + (mt * 2 + nt) * 4) * 64 + lane;
                float v0 = (o[mt][nt][0] + Om[base])       * inv[nt];
                float v1 = (o[mt][nt][1] + Om[base + 64])  * inv[nt];
                float v2 = (o[mt][nt][2] + Om[base + 128]) * inv[nt];
                float v3 = (o[mt][nt][3] + Om[base + 192]) * inv[nt];
                int q = qt * 64 + qh * 32 + nt * 16 + col;
                uint2 ov;
                ov.x = pk2(v0, v1);
                ov.y = pk2(v2, v3);
                *reinterpret_cast<uint2*>(ao + ((size_t)b * NX_ + q) * C_ +
                                          h * 64 + mt * 16 + quad * 4) = ov;
            }
    }
}

// ---------------- projection GEMM (4096x1024)x(1024x1024)^T, 128x64 tile ----------------
__global__ __launch_bounds__(256, 3) void proj_gemm_kernel(
    const unsigned short* __restrict__ abf,
    const unsigned short* __restrict__ wbf,
    const float* __restrict__ bias,
    float* __restrict__ out)
{
    __shared__ unsigned short As[128 * LSTR], Bs[64 * LSTR];
    int bn = blockIdx.x, bm = blockIdx.y;
    int w = threadIdx.x >> 6, l = threadIdx.x & 63;
    int quad = l >> 4, col = l & 15;
    int sarow = w * 32 + (l >> 2), sbrow = w * 16 + (l >> 2), schk = (l & 3) * 8;

    const unsigned short* Ap = abf + (size_t)(bm * 128 + sarow) * C_ + schk;
    const unsigned short* Bp = wbf + (size_t)(bn * 64 + sbrow) * C_ + schk;
    unsigned short* Aw = As + sarow * LSTR + schk;
    unsigned short* Bw = Bs + sbrow * LSTR + schk;

    f32x4 acc[2][4];
#pragma unroll
    for (int a = 0; a < 2; a++)
#pragma unroll
        for (int b = 0; b < 4; b++) acc[a][b] = (f32x4){0.f, 0.f, 0.f, 0.f};

    uint4 ar0, ar1, br0;
#define LDREG(kk_)                                                       \
    {   int kk = (kk_) * 32;                                             \
        ar0 = *reinterpret_cast<const uint4*>(Ap + kk);                  \
        ar1 = *reinterpret_cast<const uint4*>(Ap + 16 * C_ + kk);        \
        br0 = *reinterpret_cast<const uint4*>(Bp + kk);                  \
    }
#define WRTILE()                                                         \
    {   *reinterpret_cast<uint4*>(Aw)             = ar0;                 \
        *reinterpret_cast<uint4*>(Aw + 16 * LSTR) = ar1;                 \
        *reinterpret_cast<uint4*>(Bw)             = br0;                 \
    }

    LDREG(0);
    WRTILE();
    LDREG(1);
    __syncthreads();
#pragma unroll 1
    for (int it = 0; it < 32; it++) {
        bf16x8 af[2], bfr[4];
#pragma unroll
        for (int t = 0; t < 2; t++) af[t]  = ldfrag(&As[(w * 32 + t * 16 + col) * LSTR + quad * 8]);
#pragma unroll
        for (int t = 0; t < 4; t++) bfr[t] = ldfrag(&Bs[(t * 16 + col) * LSTR + quad * 8]);
#pragma unroll
        for (int mt = 0; mt < 2; mt++)
#pragma unroll
            for (int nt = 0; nt < 4; nt++)
                acc[mt][nt] = __builtin_amdgcn_mfma_f32_16x16x32_bf16(af[mt], bfr[nt], acc[mt][nt], 0, 0, 0);
        if (it < 31) {
            __syncthreads();
            WRTILE();
            LDREG(it + 2 < 31 ? it + 2 : 31);
            __syncthreads();
        }
    }
#undef LDREG
#undef WRTILE

    float bv[4];
#pragma unroll
    for (int nt = 0; nt < 4; nt++) bv[nt] = bias[bn * 64 + nt * 16 + col];
#pragma unroll
    for (int mt = 0; mt < 2; mt++)
#pragma unroll
        for (int r = 0; r < 4; r++) {
            int m = bm * 128 + w * 32 + mt * 16 + quad * 4 + r;
#pragma unroll
            for (int nt = 0; nt < 4; nt++) {
                int n = bn * 64 + nt * 16 + col;
                out[(size_t)m * C_ + n] = acc[mt][nt][r] + bv[nt];
            }
        }
}

extern "C" void kernel_launch(void* const* d_in, const int* in_sizes, int n_in,
                              void* d_out, int out_size, void* d_ws, size_t ws_size,
                              hipStream_t stream) {
    const float* x      = (const float*)d_in[0];
    const int*   uidx   = (const int*)  d_in[1];
    const float* cachek = (const float*)d_in[2];
    const float* cachev = (const float*)d_in[3];
    const float* wqkv   = (const float*)d_in[4];
    const float* bqkv   = (const float*)d_in[5];
    const float* wproj  = (const float*)d_in[6];
    const float* bproj  = (const float*)d_in[7];
    float* out = (float*)d_out;

    char* ws = (char*)d_ws;
    unsigned short* xbf  = (unsigned short*)(ws);                       // 8 MB
    unsigned short* wqbf = (unsigned short*)(ws + (8ull  << 20));       // 6 MB
    unsigned short* wpbf = (unsigned short*)(ws + (14ull << 20));       // 2 MB
    unsigned short* qb   = (unsigned short*)(ws + (16ull << 20));       // 8 MB
    unsigned short* kfb  = (unsigned short*)(ws + (24ull << 20));       // 16 MB
    unsigned short* vtb  = (unsigned short*)(ws + (40ull << 20));       // 16 MB
    unsigned short* aob  = (unsigned short*)(ws + (56ull << 20));       // 8 MB

    cvt_all_kernel<<<20480, 256, 0, stream>>>(x, wqkv, wproj, cachek, cachev,
                                              xbf, wqbf, wpbf, kfb, vtb);
    qkv_gemm_kernel <<<dim3(24, 32), 256, 0, stream>>>(xbf, wqbf, bqkv, uidx, qb, kfb, vtb);
    attn_kernel     <<<1024, 256, 0, stream>>>(qb, kfb, vtb, aob);
    proj_gemm_kernel<<<dim3(16, 32), 256, 0, stream>>>(aob, wpbf, bproj, out);
}